// Round 5
// baseline (1357.215 us; speedup 1.0000x reference)
//
#include <hip/hip_runtime.h>
#include <hip/hip_bf16.h>

#define DIV_UP(a, b) (((a) + (b) - 1) / (b))
typedef long long ll;

// ---------- runtime-dtype helpers ----------
__device__ __forceinline__ float ldf(const void* p, ll i, int bf) {
    return bf ? __bfloat162float(((const __hip_bfloat16*)p)[i]) : ((const float*)p)[i];
}
__device__ __forceinline__ int ldi(const int* p, ll i, int w) {
    return w ? p[2 * i] : p[i];
}
template <bool BF16>
__device__ __forceinline__ float ldx(const void* p, ll i) {
    return BF16 ? __bfloat162float(((const __hip_bfloat16*)p)[i]) : ((const float*)p)[i];
}
template <bool BF16>
__device__ __forceinline__ void stf(void* p, ll i, float v) {
    if (BF16)
        ((__hip_bfloat16*)p)[i] = __float2bfloat16(v);
    else
        ((float*)p)[i] = v;
}

// ---- ordered-uint encoding for float atomicMax ----
__device__ __forceinline__ unsigned fenc(float f) {
    unsigned u = __float_as_uint(f);
    return (u & 0x80000000u) ? ~u : (u | 0x80000000u);
}
__device__ __forceinline__ float fdec(unsigned u) {
    unsigned v = (u & 0x80000000u) ? (u & 0x7FFFFFFFu) : ~u;
    return __uint_as_float(v);
}
#define ENC_NEG_INF 0x007FFFFFu

// ---- weight pool offsets (f32 elements) ----
#define O_W1 0
#define O_W2 2700
#define O_W3 13950
#define O_WO 21450
#define O_B1 21600
#define O_B2 21675
#define O_B3 21825
#define O_BO 21875
#define N_WF 21878

// ---------------- dtype detection (parallel, 1 block x 256) ----------------
__global__ void k_detect(const unsigned* __restrict__ xb, const unsigned* __restrict__ eb,
                         int* __restrict__ flags) {
    __shared__ int sv[2];
    int t = threadIdx.x;
    if (t < 2) sv[t] = 0;
    __syncthreads();
    unsigned e = (xb[t] >> 7) & 0xFFu;
    int vote = (e >= 115u && e <= 133u) ? 1 : 0;
    int zero = (eb[2 * t + 1] == 0u) ? 1 : 0;
    atomicAdd(&sv[0], vote);
    atomicAdd(&sv[1], zero);
    __syncthreads();
    if (t == 0) {
        flags[0] = (sv[0] > 128) ? 1 : 0;
        flags[1] = (sv[1] > 200) ? 1 : 0;
    }
}

// ---------------- convert all weights/biases to f32 pool ----------------
__global__ void k_cvt(const void* __restrict__ W1, const void* __restrict__ b1,
                      const void* __restrict__ W2, const void* __restrict__ b2,
                      const void* __restrict__ W3, const void* __restrict__ b3,
                      const void* __restrict__ Wo, const void* __restrict__ bo,
                      float* __restrict__ wf, const int* __restrict__ flags) {
    int t = blockIdx.x * blockDim.x + threadIdx.x;
    if (t >= N_WF) return;
    int bf = flags[0];
    const void* src;
    int base;
    if (t < O_W2) {
        src = W1;
        base = O_W1;
    } else if (t < O_W3) {
        src = W2;
        base = O_W2;
    } else if (t < O_WO) {
        src = W3;
        base = O_W3;
    } else if (t < O_B1) {
        src = Wo;
        base = O_WO;
    } else if (t < O_B2) {
        src = b1;
        base = O_B1;
    } else if (t < O_B3) {
        src = b2;
        base = O_B2;
    } else if (t < O_BO) {
        src = b3;
        base = O_B3;
    } else {
        src = bo;
        base = O_BO;
    }
    wf[t] = ldf(src, t - base, bf);
}

// ---------------- CSR build ----------------
__global__ void k_zero(int* p, int n) {
    int t = blockIdx.x * blockDim.x + threadIdx.x;
    if (t < n) p[t] = 0;
}
__global__ void k_hist(const int* __restrict__ ei, int* __restrict__ cnt,
                       const int* __restrict__ flags, int E) {
    int t = blockIdx.x * blockDim.x + threadIdx.x;
    if (t >= E) return;
    atomicAdd(&cnt[ldi(ei, (ll)E + t, flags[1])], 1);
}
__global__ void k_dinvc(const int* __restrict__ cnt, float* __restrict__ dinv, int N) {
    int t = blockIdx.x * blockDim.x + threadIdx.x;
    if (t < N) dinv[t] = rsqrtf((float)cnt[t] + 1.0f);  // +1 self-loop
}
// single-block exclusive scan: cnt[N] -> rowptr[N+1]
__global__ void k_scan(const int* __restrict__ cnt, int* __restrict__ rowptr, int N) {
    __shared__ int sums[1024];
    const int tid = threadIdx.x;
    const int CH = (N + 1023) >> 10;
    const int base = tid * CH;
    int s = 0;
    for (int i = 0; i < CH; ++i) {
        int idx = base + i;
        if (idx < N) s += cnt[idx];
    }
    sums[tid] = s;
    __syncthreads();
    for (int off = 1; off < 1024; off <<= 1) {
        int v = (tid >= off) ? sums[tid - off] : 0;
        __syncthreads();
        sums[tid] += v;
        __syncthreads();
    }
    int run = (tid > 0) ? sums[tid - 1] : 0;
    for (int i = 0; i < CH; ++i) {
        int idx = base + i;
        if (idx <= N) rowptr[idx] = run;
        if (idx < N) run += cnt[idx];
    }
}
// fill interleaved (src, weight) pairs
__global__ void k_fill(const int* __restrict__ ei, const int* __restrict__ rowptr,
                       int* __restrict__ cursor, int2* __restrict__ ep,
                       const float* __restrict__ dinv, const int* __restrict__ flags, int E) {
    int t = blockIdx.x * blockDim.x + threadIdx.x;
    if (t >= E) return;
    int wi = flags[1];
    int s = ldi(ei, t, wi);
    int d = ldi(ei, (ll)E + t, wi);
    int pos = rowptr[d] + atomicAdd(&cursor[d], 1);
    int2 v;
    v.x = s;
    v.y = __float_as_int(dinv[s] * dinv[d]);
    ep[pos] = v;
}

// ---------------- CSR aggregation: Y[n] = dinv[n]^2*X[n] + sum_e w_e * X[src_e] ----------------
// wave per node; C <= 128
template <bool EXT>
__global__ void k_agg(const void* __restrict__ X, int xstride, float* __restrict__ Y, int ystride,
                      int C, const int* __restrict__ rowptr, const int2* __restrict__ ep,
                      const float* __restrict__ dinv, const int* __restrict__ flags, int N) {
    int n = blockIdx.x * 4 + (threadIdx.x >> 6);
    if (n >= N) return;
    int lane = threadIdx.x & 63;
    int bf = EXT ? flags[0] : 0;
    float di = dinv[n];
    float w0 = di * di;
    int c1 = lane + 64;
    bool has0 = lane < C, has1 = c1 < C;
    float a0 = has0 ? w0 * ldf(X, (ll)n * xstride + lane, bf) : 0.0f;
    float a1 = has1 ? w0 * ldf(X, (ll)n * xstride + c1, bf) : 0.0f;
    int j = rowptr[n];
    int je = rowptr[n + 1];
    for (; j + 1 < je; j += 2) {
        int2 v0 = ep[j];
        int2 v1 = ep[j + 1];
        int s0 = v0.x, s1 = v1.x;
        float wa = __int_as_float(v0.y), wb = __int_as_float(v1.y);
        if (has0) {
            a0 = fmaf(wa, ldf(X, (ll)s0 * xstride + lane, bf), a0);
            a0 = fmaf(wb, ldf(X, (ll)s1 * xstride + lane, bf), a0);
        }
        if (has1) {
            a1 = fmaf(wa, ldf(X, (ll)s0 * xstride + c1, bf), a1);
            a1 = fmaf(wb, ldf(X, (ll)s1 * xstride + c1, bf), a1);
        }
    }
    if (j < je) {
        int2 v0 = ep[j];
        int s0 = v0.x;
        float wa = __int_as_float(v0.y);
        if (has0) a0 = fmaf(wa, ldf(X, (ll)s0 * xstride + lane, bf), a0);
        if (has1) a1 = fmaf(wa, ldf(X, (ll)s0 * xstride + c1, bf), a1);
    }
    if (has0) Y[(ll)n * ystride + lane] = a0;
    if (has1) Y[(ll)n * ystride + c1] = a1;
}

// ---------------- register-tiled GEMM: Y = act(X @ W + b), W/b pre-converted f32 ----------------
template <int KP, int OUT, int RN, bool RELU, bool BIAS, bool BF16_IN, bool BF16_OUT>
__global__ __launch_bounds__(256, 4) void k_gemm(const void* __restrict__ Xv, int xstride,
                                                 void* __restrict__ Yv, int ystride,
                                                 const float* __restrict__ W,
                                                 const float* __restrict__ bias, int N) {
    constexpr int OUTP = 16 * RN;
    constexpr int BK = 40;
    constexpr int NCH = (KP + BK - 1) / BK;
    __shared__ float Xs[BK][68];
    __shared__ float Ws[BK][OUTP];
    const int tid = threadIdx.x;
    const int tn = tid & 15, to = tid >> 4;
    const int node0 = blockIdx.x * 64;
    float acc[4][RN];
#pragma unroll
    for (int m = 0; m < 4; ++m)
#pragma unroll
        for (int j = 0; j < RN; ++j) acc[m][j] = 0.0f;
    float bv[RN];
#pragma unroll
    for (int j = 0; j < RN; ++j) {
        int o = to * RN + j;
        bv[j] = (BIAS && o < OUT) ? bias[o] : 0.0f;
    }
    const int nn = tid >> 2;
    const int kb = (tid & 3) * 10;
    for (int c = 0; c < NCH; ++c) {
        const int k0 = c * BK;
        __syncthreads();
        {
            int n = node0 + nn;
#pragma unroll
            for (int i = 0; i < 10; ++i) {
                int k = kb + i;
                float v = 0.0f;
                if (n < N && (k0 + k) < KP) v = ldx<BF16_IN>(Xv, (ll)n * xstride + k0 + k);
                Xs[k][nn] = v;
            }
        }
        for (int idx = tid; idx < BK * OUTP; idx += 256) {
            int k = idx / OUTP, o = idx - k * OUTP;
            int kg = k0 + k;
            float v = 0.0f;
            if (kg < KP && o < OUT) v = W[(ll)kg * OUT + o];
            Ws[k][o] = v;
        }
        __syncthreads();
        for (int k = 0; k < BK; ++k) {
            float4 x4 = *(const float4*)&Xs[k][tn * 4];
            float wv[RN];
#pragma unroll
            for (int j = 0; j < RN; ++j) wv[j] = Ws[k][to * RN + j];
#pragma unroll
            for (int j = 0; j < RN; ++j) {
                acc[0][j] = fmaf(x4.x, wv[j], acc[0][j]);
                acc[1][j] = fmaf(x4.y, wv[j], acc[1][j]);
                acc[2][j] = fmaf(x4.z, wv[j], acc[2][j]);
                acc[3][j] = fmaf(x4.w, wv[j], acc[3][j]);
            }
        }
    }
#pragma unroll
    for (int m = 0; m < 4; ++m) {
        int n = node0 + tn * 4 + m;
        if (n >= N) continue;
#pragma unroll
        for (int j = 0; j < RN; ++j) {
            int o = to * RN + j;
            if (o >= OUT) continue;
            float v = acc[m][j] + bv[j];
            if (RELU) v = fmaxf(v, 0.0f);
            stf<BF16_OUT>(Yv, (ll)n * ystride + o, v);
        }
    }
}

// ---------------- pooled init ----------------
__global__ void k_pool_init(unsigned* pooled) {
    int t = threadIdx.x;
    if (t < 64 * 3) pooled[t] = ENC_NEG_INF;
}

// ---------------- head: z = relu(Y3 + b3) @ Wo + bo; hierarchical segment-max ----------------
__global__ void k_head(const float* __restrict__ Y3, int ystride, const float* __restrict__ wf,
                       const int* __restrict__ batch, unsigned* __restrict__ pooled,
                       const int* __restrict__ flags, int N) {
    __shared__ float Ws[50 * 3];
    __shared__ float bs[50];
    __shared__ float bos[3];
    __shared__ unsigned lmax[192];
    int wi = flags[1];
    for (int i = threadIdx.x; i < 150; i += blockDim.x) Ws[i] = wf[O_WO + i];
    for (int i = threadIdx.x; i < 50; i += blockDim.x) bs[i] = wf[O_B3 + i];
    if (threadIdx.x < 3) bos[threadIdx.x] = wf[O_BO + threadIdx.x];
    for (int i = threadIdx.x; i < 192; i += blockDim.x) lmax[i] = ENC_NEG_INF;
    __syncthreads();
    int n = blockIdx.x * blockDim.x + threadIdx.x;
    int lane = threadIdx.x & 63;
    float z0 = 0.0f, z1 = 0.0f, z2 = 0.0f;
    int g = 0;
    if (n < N) {
        z0 = bos[0];
        z1 = bos[1];
        z2 = bos[2];
        const float* y = Y3 + (ll)n * ystride;
#pragma unroll
        for (int k = 0; k < 50; ++k) {
            float h = fmaxf(y[k] + bs[k], 0.0f);
            z0 = fmaf(h, Ws[k * 3 + 0], z0);
            z1 = fmaf(h, Ws[k * 3 + 1], z1);
            z2 = fmaf(h, Ws[k * 3 + 2], z2);
        }
        g = ldi(batch, n, wi);
    }
    int g0 = __shfl(g, 0);
    unsigned long long uni = __ballot(n < N && g == g0);
    if (uni == ~0ULL) {
#pragma unroll
        for (int off = 32; off > 0; off >>= 1) {
            z0 = fmaxf(z0, __shfl_xor(z0, off));
            z1 = fmaxf(z1, __shfl_xor(z1, off));
            z2 = fmaxf(z2, __shfl_xor(z2, off));
        }
        if (lane == 0) {
            atomicMax(&lmax[g0 * 3 + 0], fenc(z0));
            atomicMax(&lmax[g0 * 3 + 1], fenc(z1));
            atomicMax(&lmax[g0 * 3 + 2], fenc(z2));
        }
    } else if (n < N) {
        atomicMax(&lmax[g * 3 + 0], fenc(z0));
        atomicMax(&lmax[g * 3 + 1], fenc(z1));
        atomicMax(&lmax[g * 3 + 2], fenc(z2));
    }
    __syncthreads();
    for (int i = threadIdx.x; i < 192; i += blockDim.x) {
        unsigned v = lmax[i];
        if (v != ENC_NEG_INF) atomicMax(&pooled[i], v);
    }
}

// ---------------- softmax over [64,3] ----------------
__global__ void k_softmax(const unsigned* __restrict__ pooled, void* __restrict__ out,
                          const int* __restrict__ flags) {
    int g = threadIdx.x;
    if (g >= 64) return;
    int bf = flags[0];
    float a = fdec(pooled[g * 3 + 0]);
    float b = fdec(pooled[g * 3 + 1]);
    float c = fdec(pooled[g * 3 + 2]);
    float m = fmaxf(a, fmaxf(b, c));
    float ea = __expf(a - m), eb = __expf(b - m), ec = __expf(c - m);
    float s = 1.0f / (ea + eb + ec);
    if (bf) {
        __hip_bfloat16* o = (__hip_bfloat16*)out;
        o[g * 3 + 0] = __float2bfloat16(ea * s);
        o[g * 3 + 1] = __float2bfloat16(eb * s);
        o[g * 3 + 2] = __float2bfloat16(ec * s);
    } else {
        float* o = (float*)out;
        o[g * 3 + 0] = ea * s;
        o[g * 3 + 1] = eb * s;
        o[g * 3 + 2] = ec * s;
    }
}

extern "C" void kernel_launch(void* const* d_in, const int* in_sizes, int n_in,
                              void* d_out, int out_size, void* d_ws, size_t ws_size,
                              hipStream_t stream) {
    const void* x = d_in[0];
    const int* ei = (const int*)d_in[1];
    const int* batch = (const int*)d_in[2];

    const int N = in_sizes[0] / 36;
    const int E = in_sizes[1] / 2;

    // ---- workspace carve ----
    char* ws = (char*)d_ws;
    size_t off = 0;
    auto carve = [&](size_t bytes) {
        char* p = ws + off;
        off = (off + bytes + 255) & ~(size_t)255;
        return p;
    };
    int* flags = (int*)carve(16);
    float* wf = (float*)carve((size_t)N_WF * 4);  // f32 weight pool
    float* dinv = (float*)carve((size_t)N * 4);
    int* cnt = (int*)carve((size_t)N * 4);
    int* rowptr = (int*)carve((size_t)(N + 1) * 4);
    int2* ep = (int2*)carve((size_t)E * 8);  // interleaved (src, weight)
    unsigned* pooled = (unsigned*)carve(768);
    char* R1 = carve((size_t)N * 304);  // A1 f32 s76 | A2 f32 s76 | T3 f32 s76
    char* R2 = carve((size_t)N * 304);  // H1 f32 s76 | H2 bf16 s152 | Y3 f32 s76

    const int B = 256;

    // 0. dtype detection + weight conversion
    k_detect<<<1, 256, 0, stream>>>((const unsigned*)x, (const unsigned*)ei, flags);
    k_cvt<<<DIV_UP(N_WF, B), B, 0, stream>>>(d_in[3], d_in[4], d_in[5], d_in[6], d_in[7], d_in[8],
                                             d_in[9], d_in[10], wf, flags);

    // 1. CSR build
    k_zero<<<DIV_UP(N, B), B, 0, stream>>>(cnt, N);
    k_hist<<<DIV_UP(E, B), B, 0, stream>>>(ei, cnt, flags, E);
    k_dinvc<<<DIV_UP(N, B), B, 0, stream>>>(cnt, dinv, N);
    k_scan<<<1, 1024, 0, stream>>>(cnt, rowptr, N);
    k_zero<<<DIV_UP(N, B), B, 0, stream>>>(cnt, N);
    k_fill<<<DIV_UP(E, B), B, 0, stream>>>(ei, rowptr, cnt, ep, dinv, flags, E);

    // 2. layer 1: aggregate x (36) -> A1, GEMM 36->75 relu -> H1
    k_agg<true><<<DIV_UP(N, 4), B, 0, stream>>>(x, 36, (float*)R1, 76, 36, rowptr, ep, dinv, flags,
                                                N);
    k_gemm<36, 75, 5, true, true, false, false>
        <<<DIV_UP(N, 64), B, 0, stream>>>(R1, 76, R2, 76, wf + O_W1, wf + O_B1, N);

    // 3. layer 2: aggregate H1 (75) -> A2, GEMM 75->150 relu -> H2 (bf16)
    k_agg<false><<<DIV_UP(N, 4), B, 0, stream>>>(R2, 76, (float*)R1, 76, 75, rowptr, ep, dinv,
                                                 flags, N);
    k_gemm<75, 150, 10, true, true, false, true>
        <<<DIV_UP(N, 64), B, 0, stream>>>(R1, 76, R2, 152, wf + O_W2, wf + O_B2, N);

    // 4. layer 3: GEMM 150->50 (no act) -> T3, aggregate (50) -> Y3
    k_gemm<150, 50, 4, false, false, true, false>
        <<<DIV_UP(N, 64), B, 0, stream>>>(R2, 152, R1, 76, wf + O_W3, nullptr, N);
    k_agg<false><<<DIV_UP(N, 4), B, 0, stream>>>(R1, 76, (float*)R2, 76, 50, rowptr, ep, dinv,
                                                 flags, N);

    // 5. head + pooling + softmax
    k_pool_init<<<1, 192, 0, stream>>>(pooled);
    k_head<<<DIV_UP(N, B), B, 0, stream>>>((const float*)R2, 76, wf, batch, pooled, flags, N);
    k_softmax<<<1, 64, 0, stream>>>(pooled, d_out, flags);
}

// Round 6
// 635.979 us; speedup vs baseline: 2.1341x; 2.1341x over previous
//
#include <hip/hip_runtime.h>
#include <hip/hip_bf16.h>

#define DIV_UP(a, b) (((a) + (b) - 1) / (b))
typedef long long ll;

// ---------- runtime-dtype helpers ----------
__device__ __forceinline__ float ldf(const void* p, ll i, int bf) {
    return bf ? __bfloat162float(((const __hip_bfloat16*)p)[i]) : ((const float*)p)[i];
}
__device__ __forceinline__ int ldi(const int* p, ll i, int w) {
    return w ? p[2 * i] : p[i];
}
template <bool BF16>
__device__ __forceinline__ float ldx(const void* p, ll i) {
    return BF16 ? __bfloat162float(((const __hip_bfloat16*)p)[i]) : ((const float*)p)[i];
}
template <bool BF16>
__device__ __forceinline__ void stf(void* p, ll i, float v) {
    if (BF16)
        ((__hip_bfloat16*)p)[i] = __float2bfloat16(v);
    else
        ((float*)p)[i] = v;
}

// ---- ordered-uint encoding for float atomicMax ----
__device__ __forceinline__ unsigned fenc(float f) {
    unsigned u = __float_as_uint(f);
    return (u & 0x80000000u) ? ~u : (u | 0x80000000u);
}
__device__ __forceinline__ float fdec(unsigned u) {
    unsigned v = (u & 0x80000000u) ? (u & 0x7FFFFFFFu) : ~u;
    return __uint_as_float(v);
}
#define ENC_NEG_INF 0x007FFFFFu

// ---- weight pool offsets (f32 elements) ----
#define O_W1 0
#define O_W2 2700
#define O_W3 13950
#define O_WO 21450
#define O_B1 21600
#define O_B2 21675
#define O_B3 21825
#define O_BO 21875
#define N_WF 21878

// ---------------- dtype detection (parallel, 1 block x 256) ----------------
__global__ void k_detect(const unsigned* __restrict__ xb, const unsigned* __restrict__ eb,
                         int* __restrict__ flags) {
    __shared__ int sv[2];
    int t = threadIdx.x;
    if (t < 2) sv[t] = 0;
    __syncthreads();
    unsigned e = (xb[t] >> 7) & 0xFFu;
    int vote = (e >= 115u && e <= 133u) ? 1 : 0;
    int zero = (eb[2 * t + 1] == 0u) ? 1 : 0;
    atomicAdd(&sv[0], vote);
    atomicAdd(&sv[1], zero);
    __syncthreads();
    if (t == 0) {
        flags[0] = (sv[0] > 128) ? 1 : 0;
        flags[1] = (sv[1] > 200) ? 1 : 0;
    }
}

// ---------------- convert all weights/biases to f32 pool ----------------
__global__ void k_cvt(const void* __restrict__ W1, const void* __restrict__ b1,
                      const void* __restrict__ W2, const void* __restrict__ b2,
                      const void* __restrict__ W3, const void* __restrict__ b3,
                      const void* __restrict__ Wo, const void* __restrict__ bo,
                      float* __restrict__ wf, const int* __restrict__ flags) {
    int t = blockIdx.x * blockDim.x + threadIdx.x;
    if (t >= N_WF) return;
    int bf = flags[0];
    const void* src;
    int base;
    if (t < O_W2) {
        src = W1;
        base = O_W1;
    } else if (t < O_W3) {
        src = W2;
        base = O_W2;
    } else if (t < O_WO) {
        src = W3;
        base = O_W3;
    } else if (t < O_B1) {
        src = Wo;
        base = O_WO;
    } else if (t < O_B2) {
        src = b1;
        base = O_B1;
    } else if (t < O_B3) {
        src = b2;
        base = O_B2;
    } else if (t < O_BO) {
        src = b3;
        base = O_B3;
    } else {
        src = bo;
        base = O_BO;
    }
    wf[t] = ldf(src, t - base, bf);
}

// ---------------- CSR build ----------------
__global__ void k_zero(int* p, int n) {
    int t = blockIdx.x * blockDim.x + threadIdx.x;
    if (t < n) p[t] = 0;
}
__global__ void k_hist(const int* __restrict__ ei, int* __restrict__ cnt,
                       const int* __restrict__ flags, int E) {
    int t = blockIdx.x * blockDim.x + threadIdx.x;
    if (t >= E) return;
    atomicAdd(&cnt[ldi(ei, (ll)E + t, flags[1])], 1);
}
__global__ void k_dinvc(const int* __restrict__ cnt, float* __restrict__ dinv, int N) {
    int t = blockIdx.x * blockDim.x + threadIdx.x;
    if (t < N) dinv[t] = rsqrtf((float)cnt[t] + 1.0f);  // +1 self-loop
}
// single-block exclusive scan: cnt[N] -> rowptr[N+1]
__global__ void k_scan(const int* __restrict__ cnt, int* __restrict__ rowptr, int N) {
    __shared__ int sums[1024];
    const int tid = threadIdx.x;
    const int CH = (N + 1023) >> 10;
    const int base = tid * CH;
    int s = 0;
    for (int i = 0; i < CH; ++i) {
        int idx = base + i;
        if (idx < N) s += cnt[idx];
    }
    sums[tid] = s;
    __syncthreads();
    for (int off = 1; off < 1024; off <<= 1) {
        int v = (tid >= off) ? sums[tid - off] : 0;
        __syncthreads();
        sums[tid] += v;
        __syncthreads();
    }
    int run = (tid > 0) ? sums[tid - 1] : 0;
    for (int i = 0; i < CH; ++i) {
        int idx = base + i;
        if (idx <= N) rowptr[idx] = run;
        if (idx < N) run += cnt[idx];
    }
}
// fill interleaved (src, weight) pairs
__global__ void k_fill(const int* __restrict__ ei, const int* __restrict__ rowptr,
                       int* __restrict__ cursor, int2* __restrict__ ep,
                       const float* __restrict__ dinv, const int* __restrict__ flags, int E) {
    int t = blockIdx.x * blockDim.x + threadIdx.x;
    if (t >= E) return;
    int wi = flags[1];
    int s = ldi(ei, t, wi);
    int d = ldi(ei, (ll)E + t, wi);
    int pos = rowptr[d] + atomicAdd(&cursor[d], 1);
    int2 v;
    v.x = s;
    v.y = __float_as_int(dinv[s] * dinv[d]);
    ep[pos] = v;
}

// ---------------- CSR aggregation: Y[n] = dinv[n]^2*X[n] + sum_e w_e * X[src_e] ----------------
// wave per node; C <= 128
template <bool EXT>
__global__ void k_agg(const void* __restrict__ X, int xstride, float* __restrict__ Y, int ystride,
                      int C, const int* __restrict__ rowptr, const int2* __restrict__ ep,
                      const float* __restrict__ dinv, const int* __restrict__ flags, int N) {
    int n = blockIdx.x * 4 + (threadIdx.x >> 6);
    if (n >= N) return;
    int lane = threadIdx.x & 63;
    int bf = EXT ? flags[0] : 0;
    float di = dinv[n];
    float w0 = di * di;
    int c1 = lane + 64;
    bool has0 = lane < C, has1 = c1 < C;
    float a0 = has0 ? w0 * ldf(X, (ll)n * xstride + lane, bf) : 0.0f;
    float a1 = has1 ? w0 * ldf(X, (ll)n * xstride + c1, bf) : 0.0f;
    int j = rowptr[n];
    int je = rowptr[n + 1];
    for (; j + 1 < je; j += 2) {
        int2 v0 = ep[j];
        int2 v1 = ep[j + 1];
        int s0 = v0.x, s1 = v1.x;
        float wa = __int_as_float(v0.y), wb = __int_as_float(v1.y);
        if (has0) {
            a0 = fmaf(wa, ldf(X, (ll)s0 * xstride + lane, bf), a0);
            a0 = fmaf(wb, ldf(X, (ll)s1 * xstride + lane, bf), a0);
        }
        if (has1) {
            a1 = fmaf(wa, ldf(X, (ll)s0 * xstride + c1, bf), a1);
            a1 = fmaf(wb, ldf(X, (ll)s1 * xstride + c1, bf), a1);
        }
    }
    if (j < je) {
        int2 v0 = ep[j];
        int s0 = v0.x;
        float wa = __int_as_float(v0.y);
        if (has0) a0 = fmaf(wa, ldf(X, (ll)s0 * xstride + lane, bf), a0);
        if (has1) a1 = fmaf(wa, ldf(X, (ll)s0 * xstride + c1, bf), a1);
    }
    if (has0) Y[(ll)n * ystride + lane] = a0;
    if (has1) Y[(ll)n * ystride + c1] = a1;
}

// ---------------- register-tiled GEMM: Y = act(X @ W + b), W/b pre-converted f32 ----------------
// NOTE: no min-waves launch_bounds arg — R5 showed (256,4) forces VGPR=64 + 1.5 GB scratch spill.
// X staging is UNGUARDED: out-of-range k reads hit row padding / adjacent rows (finite values)
// and multiply against Ws rows zeroed for kg>=KP; writeback is guarded. A pad region after the
// last buffer keeps worst-case overreads inside the workspace.
template <int KP, int OUT, int RN, bool RELU, bool BIAS, bool BF16_IN, bool BF16_OUT>
__global__ __launch_bounds__(256) void k_gemm(const void* __restrict__ Xv, int xstride,
                                              void* __restrict__ Yv, int ystride,
                                              const float* __restrict__ W,
                                              const float* __restrict__ bias, int N) {
    constexpr int OUTP = 16 * RN;
    constexpr int BK = 40;
    constexpr int NCH = (KP + BK - 1) / BK;
    __shared__ float Xs[BK][68];
    __shared__ float Ws[BK][OUTP];
    const int tid = threadIdx.x;
    const int tn = tid & 15, to = tid >> 4;
    const int node0 = blockIdx.x * 64;
    float acc[4][RN];
#pragma unroll
    for (int m = 0; m < 4; ++m)
#pragma unroll
        for (int j = 0; j < RN; ++j) acc[m][j] = 0.0f;
    float bv[RN];
#pragma unroll
    for (int j = 0; j < RN; ++j) {
        int o = to * RN + j;
        bv[j] = (BIAS && o < OUT) ? bias[o] : 0.0f;
    }
    const int nn = tid >> 2;
    const int kb = (tid & 3) * 10;
    const ll xrow = (ll)(node0 + nn) * xstride + kb;
    for (int c = 0; c < NCH; ++c) {
        const int k0 = c * BK;
        __syncthreads();
#pragma unroll
        for (int i = 0; i < 10; ++i) Xs[kb + i][nn] = ldx<BF16_IN>(Xv, xrow + k0 + i);
        for (int idx = tid; idx < BK * OUTP; idx += 256) {
            int k = idx / OUTP, o = idx - k * OUTP;
            int kg = k0 + k;
            float v = 0.0f;
            if (kg < KP && o < OUT) v = W[(ll)kg * OUT + o];
            Ws[k][o] = v;
        }
        __syncthreads();
        for (int k = 0; k < BK; ++k) {
            float4 x4 = *(const float4*)&Xs[k][tn * 4];
            float wv[RN];
#pragma unroll
            for (int j = 0; j < RN; ++j) wv[j] = Ws[k][to * RN + j];
#pragma unroll
            for (int j = 0; j < RN; ++j) {
                acc[0][j] = fmaf(x4.x, wv[j], acc[0][j]);
                acc[1][j] = fmaf(x4.y, wv[j], acc[1][j]);
                acc[2][j] = fmaf(x4.z, wv[j], acc[2][j]);
                acc[3][j] = fmaf(x4.w, wv[j], acc[3][j]);
            }
        }
    }
#pragma unroll
    for (int m = 0; m < 4; ++m) {
        int n = node0 + tn * 4 + m;
        if (n >= N) continue;
#pragma unroll
        for (int j = 0; j < RN; ++j) {
            int o = to * RN + j;
            if (o >= OUT) continue;
            float v = acc[m][j] + bv[j];
            if (RELU) v = fmaxf(v, 0.0f);
            stf<BF16_OUT>(Yv, (ll)n * ystride + o, v);
        }
    }
}

// ---------------- pooled init ----------------
__global__ void k_pool_init(unsigned* pooled) {
    int t = threadIdx.x;
    if (t < 64 * 3) pooled[t] = ENC_NEG_INF;
}

// ---------------- head: z = relu(Y3 + b3) @ Wo + bo; hierarchical segment-max ----------------
__global__ void k_head(const float* __restrict__ Y3, int ystride, const float* __restrict__ wf,
                       const int* __restrict__ batch, unsigned* __restrict__ pooled,
                       const int* __restrict__ flags, int N) {
    __shared__ float Ws[50 * 3];
    __shared__ float bs[50];
    __shared__ float bos[3];
    __shared__ unsigned lmax[192];
    int wi = flags[1];
    for (int i = threadIdx.x; i < 150; i += blockDim.x) Ws[i] = wf[O_WO + i];
    for (int i = threadIdx.x; i < 50; i += blockDim.x) bs[i] = wf[O_B3 + i];
    if (threadIdx.x < 3) bos[threadIdx.x] = wf[O_BO + threadIdx.x];
    for (int i = threadIdx.x; i < 192; i += blockDim.x) lmax[i] = ENC_NEG_INF;
    __syncthreads();
    int n = blockIdx.x * blockDim.x + threadIdx.x;
    int lane = threadIdx.x & 63;
    float z0 = 0.0f, z1 = 0.0f, z2 = 0.0f;
    int g = 0;
    if (n < N) {
        z0 = bos[0];
        z1 = bos[1];
        z2 = bos[2];
        const float* y = Y3 + (ll)n * ystride;
#pragma unroll
        for (int k = 0; k < 50; ++k) {
            float h = fmaxf(y[k] + bs[k], 0.0f);
            z0 = fmaf(h, Ws[k * 3 + 0], z0);
            z1 = fmaf(h, Ws[k * 3 + 1], z1);
            z2 = fmaf(h, Ws[k * 3 + 2], z2);
        }
        g = ldi(batch, n, wi);
    }
    int g0 = __shfl(g, 0);
    unsigned long long uni = __ballot(n < N && g == g0);
    if (uni == ~0ULL) {
#pragma unroll
        for (int off = 32; off > 0; off >>= 1) {
            z0 = fmaxf(z0, __shfl_xor(z0, off));
            z1 = fmaxf(z1, __shfl_xor(z1, off));
            z2 = fmaxf(z2, __shfl_xor(z2, off));
        }
        if (lane == 0) {
            atomicMax(&lmax[g0 * 3 + 0], fenc(z0));
            atomicMax(&lmax[g0 * 3 + 1], fenc(z1));
            atomicMax(&lmax[g0 * 3 + 2], fenc(z2));
        }
    } else if (n < N) {
        atomicMax(&lmax[g * 3 + 0], fenc(z0));
        atomicMax(&lmax[g * 3 + 1], fenc(z1));
        atomicMax(&lmax[g * 3 + 2], fenc(z2));
    }
    __syncthreads();
    for (int i = threadIdx.x; i < 192; i += blockDim.x) {
        unsigned v = lmax[i];
        if (v != ENC_NEG_INF) atomicMax(&pooled[i], v);
    }
}

// ---------------- softmax over [64,3] ----------------
__global__ void k_softmax(const unsigned* __restrict__ pooled, void* __restrict__ out,
                          const int* __restrict__ flags) {
    int g = threadIdx.x;
    if (g >= 64) return;
    int bf = flags[0];
    float a = fdec(pooled[g * 3 + 0]);
    float b = fdec(pooled[g * 3 + 1]);
    float c = fdec(pooled[g * 3 + 2]);
    float m = fmaxf(a, fmaxf(b, c));
    float ea = __expf(a - m), eb = __expf(b - m), ec = __expf(c - m);
    float s = 1.0f / (ea + eb + ec);
    if (bf) {
        __hip_bfloat16* o = (__hip_bfloat16*)out;
        o[g * 3 + 0] = __float2bfloat16(ea * s);
        o[g * 3 + 1] = __float2bfloat16(eb * s);
        o[g * 3 + 2] = __float2bfloat16(ec * s);
    } else {
        float* o = (float*)out;
        o[g * 3 + 0] = ea * s;
        o[g * 3 + 1] = eb * s;
        o[g * 3 + 2] = ec * s;
    }
}

extern "C" void kernel_launch(void* const* d_in, const int* in_sizes, int n_in,
                              void* d_out, int out_size, void* d_ws, size_t ws_size,
                              hipStream_t stream) {
    const void* x = d_in[0];
    const int* ei = (const int*)d_in[1];
    const int* batch = (const int*)d_in[2];

    const int N = in_sizes[0] / 36;
    const int E = in_sizes[1] / 2;

    // ---- workspace carve ----
    char* ws = (char*)d_ws;
    size_t off = 0;
    auto carve = [&](size_t bytes) {
        char* p = ws + off;
        off = (off + bytes + 255) & ~(size_t)255;
        return p;
    };
    int* flags = (int*)carve(16);
    float* wf = (float*)carve((size_t)N_WF * 4);  // f32 weight pool
    float* dinv = (float*)carve((size_t)N * 4);
    int* cnt = (int*)carve((size_t)N * 4);
    int* rowptr = (int*)carve((size_t)(N + 1) * 4);
    int2* ep = (int2*)carve((size_t)E * 8);  // interleaved (src, weight)
    unsigned* pooled = (unsigned*)carve(768);
    char* R1 = carve((size_t)N * 304);  // A1 f32 s76 | A2 f32 s76 | T3 f32 s76
    char* R2 = carve((size_t)N * 304);  // H1 f32 s76 | H2 bf16 s152 | Y3 f32 s76
    (void)carve(65536);                 // pad: unguarded GEMM staging may overread past R2

    const int B = 256;

    // 0. dtype detection + weight conversion
    k_detect<<<1, 256, 0, stream>>>((const unsigned*)x, (const unsigned*)ei, flags);
    k_cvt<<<DIV_UP(N_WF, B), B, 0, stream>>>(d_in[3], d_in[4], d_in[5], d_in[6], d_in[7], d_in[8],
                                             d_in[9], d_in[10], wf, flags);

    // 1. CSR build
    k_zero<<<DIV_UP(N, B), B, 0, stream>>>(cnt, N);
    k_hist<<<DIV_UP(E, B), B, 0, stream>>>(ei, cnt, flags, E);
    k_dinvc<<<DIV_UP(N, B), B, 0, stream>>>(cnt, dinv, N);
    k_scan<<<1, 1024, 0, stream>>>(cnt, rowptr, N);
    k_zero<<<DIV_UP(N, B), B, 0, stream>>>(cnt, N);
    k_fill<<<DIV_UP(E, B), B, 0, stream>>>(ei, rowptr, cnt, ep, dinv, flags, E);

    // 2. layer 1: aggregate x (36) -> A1, GEMM 36->75 relu -> H1
    k_agg<true><<<DIV_UP(N, 4), B, 0, stream>>>(x, 36, (float*)R1, 76, 36, rowptr, ep, dinv, flags,
                                                N);
    k_gemm<36, 75, 5, true, true, false, false>
        <<<DIV_UP(N, 64), B, 0, stream>>>(R1, 76, R2, 76, wf + O_W1, wf + O_B1, N);

    // 3. layer 2: aggregate H1 (75) -> A2, GEMM 75->150 relu -> H2 (bf16)
    k_agg<false><<<DIV_UP(N, 4), B, 0, stream>>>(R2, 76, (float*)R1, 76, 75, rowptr, ep, dinv,
                                                 flags, N);
    k_gemm<75, 150, 10, true, true, false, true>
        <<<DIV_UP(N, 64), B, 0, stream>>>(R1, 76, R2, 152, wf + O_W2, wf + O_B2, N);

    // 4. layer 3: GEMM 150->50 (no act) -> T3, aggregate (50) -> Y3
    k_gemm<150, 50, 4, false, false, true, false>
        <<<DIV_UP(N, 64), B, 0, stream>>>(R2, 152, R1, 76, wf + O_W3, nullptr, N);
    k_agg<false><<<DIV_UP(N, 4), B, 0, stream>>>(R1, 76, (float*)R2, 76, 50, rowptr, ep, dinv,
                                                 flags, N);

    // 5. head + pooling + softmax
    k_pool_init<<<1, 192, 0, stream>>>(pooled);
    k_head<<<DIV_UP(N, B), B, 0, stream>>>((const float*)R2, 76, wf, batch, pooled, flags, N);
    k_softmax<<<1, 64, 0, stream>>>(pooled, d_out, flags);
}

// Round 7
// 467.276 us; speedup vs baseline: 2.9045x; 1.3610x over previous
//
#include <hip/hip_runtime.h>
#include <hip/hip_bf16.h>

#define DIV_UP(a, b) (((a) + (b) - 1) / (b))
typedef long long ll;

// ---------- runtime-dtype helpers ----------
__device__ __forceinline__ float ldf(const void* p, ll i, int bf) {
    return bf ? __bfloat162float(((const __hip_bfloat16*)p)[i]) : ((const float*)p)[i];
}
__device__ __forceinline__ int ldi(const int* p, ll i, int w) {
    return w ? p[2 * i] : p[i];
}
template <bool BF16>
__device__ __forceinline__ float ldx(const void* p, ll i) {
    return BF16 ? __bfloat162float(((const __hip_bfloat16*)p)[i]) : ((const float*)p)[i];
}
template <bool BF16>
__device__ __forceinline__ void stf(void* p, ll i, float v) {
    if (BF16)
        ((__hip_bfloat16*)p)[i] = __float2bfloat16(v);
    else
        ((float*)p)[i] = v;
}

// ---- ordered-uint encoding for float atomicMax ----
__device__ __forceinline__ unsigned fenc(float f) {
    unsigned u = __float_as_uint(f);
    return (u & 0x80000000u) ? ~u : (u | 0x80000000u);
}
__device__ __forceinline__ float fdec(unsigned u) {
    unsigned v = (u & 0x80000000u) ? (u & 0x7FFFFFFFu) : ~u;
    return __uint_as_float(v);
}
#define ENC_NEG_INF 0x007FFFFFu

// ---- weight pool offsets (f32 elements) ----
#define O_W1 0
#define O_W2 2700
#define O_W3 13950
#define O_WO 21450
#define O_B1 21600
#define O_B2 21675
#define O_B3 21825
#define O_BO 21875
#define N_WF 21878

// ---------------- dtype detection (parallel, 1 block x 256) ----------------
__global__ void k_detect(const unsigned* __restrict__ xb, const unsigned* __restrict__ eb,
                         int* __restrict__ flags) {
    __shared__ int sv[2];
    int t = threadIdx.x;
    if (t < 2) sv[t] = 0;
    __syncthreads();
    unsigned e = (xb[t] >> 7) & 0xFFu;
    int vote = (e >= 115u && e <= 133u) ? 1 : 0;
    int zero = (eb[2 * t + 1] == 0u) ? 1 : 0;
    atomicAdd(&sv[0], vote);
    atomicAdd(&sv[1], zero);
    __syncthreads();
    if (t == 0) {
        flags[0] = (sv[0] > 128) ? 1 : 0;
        flags[1] = (sv[1] > 200) ? 1 : 0;
    }
}

// ---------------- convert all weights/biases to f32 pool ----------------
__global__ void k_cvt(const void* __restrict__ W1, const void* __restrict__ b1,
                      const void* __restrict__ W2, const void* __restrict__ b2,
                      const void* __restrict__ W3, const void* __restrict__ b3,
                      const void* __restrict__ Wo, const void* __restrict__ bo,
                      float* __restrict__ wf, const int* __restrict__ flags) {
    int t = blockIdx.x * blockDim.x + threadIdx.x;
    if (t >= N_WF) return;
    int bf = flags[0];
    const void* src;
    int base;
    if (t < O_W2) {
        src = W1;
        base = O_W1;
    } else if (t < O_W3) {
        src = W2;
        base = O_W2;
    } else if (t < O_WO) {
        src = W3;
        base = O_W3;
    } else if (t < O_B1) {
        src = Wo;
        base = O_WO;
    } else if (t < O_B2) {
        src = b1;
        base = O_B1;
    } else if (t < O_B3) {
        src = b2;
        base = O_B2;
    } else if (t < O_BO) {
        src = b3;
        base = O_B3;
    } else {
        src = bo;
        base = O_BO;
    }
    wf[t] = ldf(src, t - base, bf);
}

// ---------------- CSR build ----------------
__global__ void k_zero(int* p, int n) {
    int t = blockIdx.x * blockDim.x + threadIdx.x;
    if (t < n) p[t] = 0;
}
__global__ void k_hist(const int* __restrict__ ei, int* __restrict__ cnt,
                       const int* __restrict__ flags, int E) {
    int t = blockIdx.x * blockDim.x + threadIdx.x;
    if (t >= E) return;
    atomicAdd(&cnt[ldi(ei, (ll)E + t, flags[1])], 1);
}
__global__ void k_dinvc(const int* __restrict__ cnt, float* __restrict__ dinv, int N) {
    int t = blockIdx.x * blockDim.x + threadIdx.x;
    if (t < N) dinv[t] = rsqrtf((float)cnt[t] + 1.0f);  // +1 self-loop
}
// single-block exclusive scan: cnt[N] -> rowptr[N+1]
__global__ void k_scan(const int* __restrict__ cnt, int* __restrict__ rowptr, int N) {
    __shared__ int sums[1024];
    const int tid = threadIdx.x;
    const int CH = (N + 1023) >> 10;
    const int base = tid * CH;
    int s = 0;
    for (int i = 0; i < CH; ++i) {
        int idx = base + i;
        if (idx < N) s += cnt[idx];
    }
    sums[tid] = s;
    __syncthreads();
    for (int off = 1; off < 1024; off <<= 1) {
        int v = (tid >= off) ? sums[tid - off] : 0;
        __syncthreads();
        sums[tid] += v;
        __syncthreads();
    }
    int run = (tid > 0) ? sums[tid - 1] : 0;
    for (int i = 0; i < CH; ++i) {
        int idx = base + i;
        if (idx <= N) rowptr[idx] = run;
        if (idx < N) run += cnt[idx];
    }
}
// fill interleaved (src, weight) pairs
__global__ void k_fill(const int* __restrict__ ei, const int* __restrict__ rowptr,
                       int* __restrict__ cursor, int2* __restrict__ ep,
                       const float* __restrict__ dinv, const int* __restrict__ flags, int E) {
    int t = blockIdx.x * blockDim.x + threadIdx.x;
    if (t >= E) return;
    int wi = flags[1];
    int s = ldi(ei, t, wi);
    int d = ldi(ei, (ll)E + t, wi);
    int pos = rowptr[d] + atomicAdd(&cursor[d], 1);
    int2 v;
    v.x = s;
    v.y = __float_as_int(dinv[s] * dinv[d]);
    ep[pos] = v;
}

// ---------------- CSR aggregation: Y[n] = dinv[n]^2*X[n] + sum_e w_e * X[src_e] ----------------
// wave per node; C <= 128
template <bool EXT>
__global__ void k_agg(const void* __restrict__ X, int xstride, float* __restrict__ Y, int ystride,
                      int C, const int* __restrict__ rowptr, const int2* __restrict__ ep,
                      const float* __restrict__ dinv, const int* __restrict__ flags, int N) {
    int n = blockIdx.x * 4 + (threadIdx.x >> 6);
    if (n >= N) return;
    int lane = threadIdx.x & 63;
    int bf = EXT ? flags[0] : 0;
    float di = dinv[n];
    float w0 = di * di;
    int c1 = lane + 64;
    bool has0 = lane < C, has1 = c1 < C;
    float a0 = has0 ? w0 * ldf(X, (ll)n * xstride + lane, bf) : 0.0f;
    float a1 = has1 ? w0 * ldf(X, (ll)n * xstride + c1, bf) : 0.0f;
    int j = rowptr[n];
    int je = rowptr[n + 1];
    for (; j + 1 < je; j += 2) {
        int2 v0 = ep[j];
        int2 v1 = ep[j + 1];
        int s0 = v0.x, s1 = v1.x;
        float wa = __int_as_float(v0.y), wb = __int_as_float(v1.y);
        if (has0) {
            a0 = fmaf(wa, ldf(X, (ll)s0 * xstride + lane, bf), a0);
            a0 = fmaf(wb, ldf(X, (ll)s1 * xstride + lane, bf), a0);
        }
        if (has1) {
            a1 = fmaf(wa, ldf(X, (ll)s0 * xstride + c1, bf), a1);
            a1 = fmaf(wb, ldf(X, (ll)s1 * xstride + c1, bf), a1);
        }
    }
    if (j < je) {
        int2 v0 = ep[j];
        int s0 = v0.x;
        float wa = __int_as_float(v0.y);
        if (has0) a0 = fmaf(wa, ldf(X, (ll)s0 * xstride + lane, bf), a0);
        if (has1) a1 = fmaf(wa, ldf(X, (ll)s0 * xstride + c1, bf), a1);
    }
    if (has0) Y[(ll)n * ystride + lane] = a0;
    if (has1) Y[(ll)n * ystride + c1] = a1;
}

// ---------------- register-tiled GEMM: Y = act(X @ W + b), W/b pre-converted f32 ----------------
// R6 post-mortem: full unroll of the BK=40 compute loop made the compiler hoist all 40 iterations'
// LDS loads -> ~360+ live VGPRs -> 256-cap + 258 MB scratch spill. `#pragma unroll 4` bounds the
// live set to ~4*(4+RN)+acc. X staging unguarded (pad region in ws); writeback guarded.
template <int KP, int OUT, int RN, bool RELU, bool BIAS, bool BF16_IN, bool BF16_OUT>
__global__ __launch_bounds__(256) void k_gemm(const void* __restrict__ Xv, int xstride,
                                              void* __restrict__ Yv, int ystride,
                                              const float* __restrict__ W,
                                              const float* __restrict__ bias, int N) {
    constexpr int OUTP = 16 * RN;
    constexpr int BK = 40;
    constexpr int NCH = (KP + BK - 1) / BK;
    __shared__ float Xs[BK][68];
    __shared__ float Ws[BK][OUTP];
    const int tid = threadIdx.x;
    const int tn = tid & 15, to = tid >> 4;
    const int node0 = blockIdx.x * 64;
    float acc[4][RN];
#pragma unroll
    for (int m = 0; m < 4; ++m)
#pragma unroll
        for (int j = 0; j < RN; ++j) acc[m][j] = 0.0f;
    float bv[RN];
#pragma unroll
    for (int j = 0; j < RN; ++j) {
        int o = to * RN + j;
        bv[j] = (BIAS && o < OUT) ? bias[o] : 0.0f;
    }
    const int nn = tid >> 2;
    const int kb = (tid & 3) * 10;
    const ll xrow = (ll)(node0 + nn) * xstride + kb;
    for (int c = 0; c < NCH; ++c) {
        const int k0 = c * BK;
        __syncthreads();
#pragma unroll
        for (int i = 0; i < 10; ++i) Xs[kb + i][nn] = ldx<BF16_IN>(Xv, xrow + k0 + i);
        for (int idx = tid; idx < BK * OUTP; idx += 256) {
            int k = idx / OUTP, o = idx - k * OUTP;
            int kg = k0 + k;
            float v = 0.0f;
            if (kg < KP && o < OUT) v = W[(ll)kg * OUT + o];
            Ws[k][o] = v;
        }
        __syncthreads();
#pragma unroll 4
        for (int k = 0; k < BK; ++k) {
            float4 x4 = *(const float4*)&Xs[k][tn * 4];
            float wv[RN];
#pragma unroll
            for (int j = 0; j < RN; ++j) wv[j] = Ws[k][to * RN + j];
#pragma unroll
            for (int j = 0; j < RN; ++j) {
                acc[0][j] = fmaf(x4.x, wv[j], acc[0][j]);
                acc[1][j] = fmaf(x4.y, wv[j], acc[1][j]);
                acc[2][j] = fmaf(x4.z, wv[j], acc[2][j]);
                acc[3][j] = fmaf(x4.w, wv[j], acc[3][j]);
            }
        }
    }
#pragma unroll
    for (int m = 0; m < 4; ++m) {
        int n = node0 + tn * 4 + m;
        if (n >= N) continue;
#pragma unroll
        for (int j = 0; j < RN; ++j) {
            int o = to * RN + j;
            if (o >= OUT) continue;
            float v = acc[m][j] + bv[j];
            if (RELU) v = fmaxf(v, 0.0f);
            stf<BF16_OUT>(Yv, (ll)n * ystride + o, v);
        }
    }
}

// ---------------- pooled init ----------------
__global__ void k_pool_init(unsigned* pooled) {
    int t = threadIdx.x;
    if (t < 64 * 3) pooled[t] = ENC_NEG_INF;
}

// ---------------- head: z = relu(Y3 + b3) @ Wo + bo; hierarchical segment-max ----------------
__global__ void k_head(const float* __restrict__ Y3, int ystride, const float* __restrict__ wf,
                       const int* __restrict__ batch, unsigned* __restrict__ pooled,
                       const int* __restrict__ flags, int N) {
    __shared__ float Ws[50 * 3];
    __shared__ float bs[50];
    __shared__ float bos[3];
    __shared__ unsigned lmax[192];
    int wi = flags[1];
    for (int i = threadIdx.x; i < 150; i += blockDim.x) Ws[i] = wf[O_WO + i];
    for (int i = threadIdx.x; i < 50; i += blockDim.x) bs[i] = wf[O_B3 + i];
    if (threadIdx.x < 3) bos[threadIdx.x] = wf[O_BO + threadIdx.x];
    for (int i = threadIdx.x; i < 192; i += blockDim.x) lmax[i] = ENC_NEG_INF;
    __syncthreads();
    int n = blockIdx.x * blockDim.x + threadIdx.x;
    int lane = threadIdx.x & 63;
    float z0 = 0.0f, z1 = 0.0f, z2 = 0.0f;
    int g = 0;
    if (n < N) {
        z0 = bos[0];
        z1 = bos[1];
        z2 = bos[2];
        const float* y = Y3 + (ll)n * ystride;
#pragma unroll
        for (int k = 0; k < 50; ++k) {
            float h = fmaxf(y[k] + bs[k], 0.0f);
            z0 = fmaf(h, Ws[k * 3 + 0], z0);
            z1 = fmaf(h, Ws[k * 3 + 1], z1);
            z2 = fmaf(h, Ws[k * 3 + 2], z2);
        }
        g = ldi(batch, n, wi);
    }
    int g0 = __shfl(g, 0);
    unsigned long long uni = __ballot(n < N && g == g0);
    if (uni == ~0ULL) {
#pragma unroll
        for (int off = 32; off > 0; off >>= 1) {
            z0 = fmaxf(z0, __shfl_xor(z0, off));
            z1 = fmaxf(z1, __shfl_xor(z1, off));
            z2 = fmaxf(z2, __shfl_xor(z2, off));
        }
        if (lane == 0) {
            atomicMax(&lmax[g0 * 3 + 0], fenc(z0));
            atomicMax(&lmax[g0 * 3 + 1], fenc(z1));
            atomicMax(&lmax[g0 * 3 + 2], fenc(z2));
        }
    } else if (n < N) {
        atomicMax(&lmax[g * 3 + 0], fenc(z0));
        atomicMax(&lmax[g * 3 + 1], fenc(z1));
        atomicMax(&lmax[g * 3 + 2], fenc(z2));
    }
    __syncthreads();
    for (int i = threadIdx.x; i < 192; i += blockDim.x) {
        unsigned v = lmax[i];
        if (v != ENC_NEG_INF) atomicMax(&pooled[i], v);
    }
}

// ---------------- softmax over [64,3] ----------------
__global__ void k_softmax(const unsigned* __restrict__ pooled, void* __restrict__ out,
                          const int* __restrict__ flags) {
    int g = threadIdx.x;
    if (g >= 64) return;
    int bf = flags[0];
    float a = fdec(pooled[g * 3 + 0]);
    float b = fdec(pooled[g * 3 + 1]);
    float c = fdec(pooled[g * 3 + 2]);
    float m = fmaxf(a, fmaxf(b, c));
    float ea = __expf(a - m), eb = __expf(b - m), ec = __expf(c - m);
    float s = 1.0f / (ea + eb + ec);
    if (bf) {
        __hip_bfloat16* o = (__hip_bfloat16*)out;
        o[g * 3 + 0] = __float2bfloat16(ea * s);
        o[g * 3 + 1] = __float2bfloat16(eb * s);
        o[g * 3 + 2] = __float2bfloat16(ec * s);
    } else {
        float* o = (float*)out;
        o[g * 3 + 0] = ea * s;
        o[g * 3 + 1] = eb * s;
        o[g * 3 + 2] = ec * s;
    }
}

extern "C" void kernel_launch(void* const* d_in, const int* in_sizes, int n_in,
                              void* d_out, int out_size, void* d_ws, size_t ws_size,
                              hipStream_t stream) {
    const void* x = d_in[0];
    const int* ei = (const int*)d_in[1];
    const int* batch = (const int*)d_in[2];

    const int N = in_sizes[0] / 36;
    const int E = in_sizes[1] / 2;

    // ---- workspace carve ----
    char* ws = (char*)d_ws;
    size_t off = 0;
    auto carve = [&](size_t bytes) {
        char* p = ws + off;
        off = (off + bytes + 255) & ~(size_t)255;
        return p;
    };
    int* flags = (int*)carve(16);
    float* wf = (float*)carve((size_t)N_WF * 4);  // f32 weight pool
    float* dinv = (float*)carve((size_t)N * 4);
    int* cnt = (int*)carve((size_t)N * 4);
    int* rowptr = (int*)carve((size_t)(N + 1) * 4);
    int2* ep = (int2*)carve((size_t)E * 8);  // interleaved (src, weight)
    unsigned* pooled = (unsigned*)carve(768);
    char* R1 = carve((size_t)N * 304);  // A1 f32 s76 | A2 f32 s76 | T3 f32 s76
    char* R2 = carve((size_t)N * 304);  // H1 f32 s76 | H2 bf16 s152 | Y3 f32 s76
    (void)carve(65536);                 // pad: unguarded GEMM staging may overread past R2

    const int B = 256;

    // 0. dtype detection + weight conversion
    k_detect<<<1, 256, 0, stream>>>((const unsigned*)x, (const unsigned*)ei, flags);
    k_cvt<<<DIV_UP(N_WF, B), B, 0, stream>>>(d_in[3], d_in[4], d_in[5], d_in[6], d_in[7], d_in[8],
                                             d_in[9], d_in[10], wf, flags);

    // 1. CSR build
    k_zero<<<DIV_UP(N, B), B, 0, stream>>>(cnt, N);
    k_hist<<<DIV_UP(E, B), B, 0, stream>>>(ei, cnt, flags, E);
    k_dinvc<<<DIV_UP(N, B), B, 0, stream>>>(cnt, dinv, N);
    k_scan<<<1, 1024, 0, stream>>>(cnt, rowptr, N);
    k_zero<<<DIV_UP(N, B), B, 0, stream>>>(cnt, N);
    k_fill<<<DIV_UP(E, B), B, 0, stream>>>(ei, rowptr, cnt, ep, dinv, flags, E);

    // 2. layer 1: aggregate x (36) -> A1, GEMM 36->75 relu -> H1
    k_agg<true><<<DIV_UP(N, 4), B, 0, stream>>>(x, 36, (float*)R1, 76, 36, rowptr, ep, dinv, flags,
                                                N);
    k_gemm<36, 75, 5, true, true, false, false>
        <<<DIV_UP(N, 64), B, 0, stream>>>(R1, 76, R2, 76, wf + O_W1, wf + O_B1, N);

    // 3. layer 2: aggregate H1 (75) -> A2, GEMM 75->150 relu -> H2 (bf16)
    k_agg<false><<<DIV_UP(N, 4), B, 0, stream>>>(R2, 76, (float*)R1, 76, 75, rowptr, ep, dinv,
                                                 flags, N);
    k_gemm<75, 150, 10, true, true, false, true>
        <<<DIV_UP(N, 64), B, 0, stream>>>(R1, 76, R2, 152, wf + O_W2, wf + O_B2, N);

    // 4. layer 3: GEMM 150->50 (no act) -> T3, aggregate (50) -> Y3
    k_gemm<150, 50, 4, false, false, true, false>
        <<<DIV_UP(N, 64), B, 0, stream>>>(R2, 152, R1, 76, wf + O_W3, nullptr, N);
    k_agg<false><<<DIV_UP(N, 4), B, 0, stream>>>(R1, 76, (float*)R2, 76, 50, rowptr, ep, dinv,
                                                 flags, N);

    // 5. head + pooling + softmax
    k_pool_init<<<1, 192, 0, stream>>>(pooled);
    k_head<<<DIV_UP(N, B), B, 0, stream>>>((const float*)R2, 76, wf, batch, pooled, flags, N);
    k_softmax<<<1, 64, 0, stream>>>(pooled, d_out, flags);
}

// Round 8
// 378.605 us; speedup vs baseline: 3.5848x; 1.2342x over previous
//
#include <hip/hip_runtime.h>
#include <hip/hip_bf16.h>

#define DIV_UP(a, b) (((a) + (b) - 1) / (b))
typedef long long ll;

// ---------- runtime-dtype helpers ----------
__device__ __forceinline__ float ldf(const void* p, ll i, int bf) {
    return bf ? __bfloat162float(((const __hip_bfloat16*)p)[i]) : ((const float*)p)[i];
}
__device__ __forceinline__ int ldi(const int* p, ll i, int w) {
    return w ? p[2 * i] : p[i];
}
template <bool BF16>
__device__ __forceinline__ float ldx(const void* p, ll i) {
    return BF16 ? __bfloat162float(((const __hip_bfloat16*)p)[i]) : ((const float*)p)[i];
}
template <bool BF16>
__device__ __forceinline__ void stf(void* p, ll i, float v) {
    if (BF16)
        ((__hip_bfloat16*)p)[i] = __float2bfloat16(v);
    else
        ((float*)p)[i] = v;
}

// ---- ordered-uint encoding for float atomicMax ----
__device__ __forceinline__ unsigned fenc(float f) {
    unsigned u = __float_as_uint(f);
    return (u & 0x80000000u) ? ~u : (u | 0x80000000u);
}
__device__ __forceinline__ float fdec(unsigned u) {
    unsigned v = (u & 0x80000000u) ? (u & 0x7FFFFFFFu) : ~u;
    return __uint_as_float(v);
}
#define ENC_NEG_INF 0x007FFFFFu

// ---- weight pool offsets (f32 elements) ----
#define O_W1 0
#define O_W2 2700
#define O_W3 13950
#define O_WO 21450
#define O_B1 21600
#define O_B2 21675
#define O_B3 21825
#define O_BO 21875
#define N_WF 21878

// ---------------- dtype detection (parallel, 1 block x 256) ----------------
__global__ void k_detect(const unsigned* __restrict__ xb, const unsigned* __restrict__ eb,
                         int* __restrict__ flags) {
    __shared__ int sv[2];
    int t = threadIdx.x;
    if (t < 2) sv[t] = 0;
    __syncthreads();
    unsigned e = (xb[t] >> 7) & 0xFFu;
    int vote = (e >= 115u && e <= 133u) ? 1 : 0;
    int zero = (eb[2 * t + 1] == 0u) ? 1 : 0;
    atomicAdd(&sv[0], vote);
    atomicAdd(&sv[1], zero);
    __syncthreads();
    if (t == 0) {
        flags[0] = (sv[0] > 128) ? 1 : 0;
        flags[1] = (sv[1] > 200) ? 1 : 0;
    }
}

// ---------------- convert all weights/biases to f32 pool ----------------
__global__ void k_cvt(const void* __restrict__ W1, const void* __restrict__ b1,
                      const void* __restrict__ W2, const void* __restrict__ b2,
                      const void* __restrict__ W3, const void* __restrict__ b3,
                      const void* __restrict__ Wo, const void* __restrict__ bo,
                      float* __restrict__ wf, const int* __restrict__ flags) {
    int t = blockIdx.x * blockDim.x + threadIdx.x;
    if (t >= N_WF) return;
    int bf = flags[0];
    const void* src;
    int base;
    if (t < O_W2) {
        src = W1;
        base = O_W1;
    } else if (t < O_W3) {
        src = W2;
        base = O_W2;
    } else if (t < O_WO) {
        src = W3;
        base = O_W3;
    } else if (t < O_B1) {
        src = Wo;
        base = O_WO;
    } else if (t < O_B2) {
        src = b1;
        base = O_B1;
    } else if (t < O_B3) {
        src = b2;
        base = O_B2;
    } else if (t < O_BO) {
        src = b3;
        base = O_B3;
    } else {
        src = bo;
        base = O_BO;
    }
    wf[t] = ldf(src, t - base, bf);
}

// ---------------- CSR build ----------------
__global__ void k_zero(int* p, int n) {
    int t = blockIdx.x * blockDim.x + threadIdx.x;
    if (t < n) p[t] = 0;
}
__global__ void k_hist(const int* __restrict__ ei, int* __restrict__ cnt,
                       const int* __restrict__ flags, int E) {
    int t = blockIdx.x * blockDim.x + threadIdx.x;
    if (t >= E) return;
    atomicAdd(&cnt[ldi(ei, (ll)E + t, flags[1])], 1);
}

// ---------------- multi-block exclusive scan over M=N+1 values (cnt padded w/ 0) ----------------
// phase 1: per-block tree-reduce -> bsum; fuses dinv computation (reads cnt anyway)
__global__ void k_scan1(const int* __restrict__ cnt, int* __restrict__ bsum,
                        float* __restrict__ dinv, int N) {
    __shared__ int s[256];
    int t = threadIdx.x;
    int idx = blockIdx.x * 256 + t;
    int v = (idx < N) ? cnt[idx] : 0;
    if (idx < N) dinv[idx] = rsqrtf((float)v + 1.0f);  // +1 self-loop
    s[t] = v;
    __syncthreads();
#pragma unroll
    for (int off = 128; off > 0; off >>= 1) {
        if (t < off) s[t] += s[t + off];
        __syncthreads();
    }
    if (t == 0) bsum[blockIdx.x] = s[0];
}
// phase 2: single-block exclusive scan of bsum in place (any nb, 256-chunked)
__global__ void k_scan2(int* __restrict__ bsum, int nb) {
    __shared__ int s[256];
    int t = threadIdx.x;
    int run = 0;
    for (int base = 0; base < nb; base += 256) {
        int i = base + t;
        int v = (i < nb) ? bsum[i] : 0;
        s[t] = v;
        __syncthreads();
        for (int off = 1; off < 256; off <<= 1) {
            int o = (t >= off) ? s[t - off] : 0;
            __syncthreads();
            s[t] += o;
            __syncthreads();
        }
        if (i < nb) bsum[i] = run + s[t] - v;
        run += s[255];
        __syncthreads();
    }
}
// phase 3: per-block local exclusive scan + block offset -> rowptr[0..N]
__global__ void k_scan3(const int* __restrict__ cnt, const int* __restrict__ bsum,
                        int* __restrict__ rowptr, int N) {
    __shared__ int s[256];
    int t = threadIdx.x;
    int idx = blockIdx.x * 256 + t;
    int v = (idx < N) ? cnt[idx] : 0;
    s[t] = v;
    __syncthreads();
    for (int off = 1; off < 256; off <<= 1) {
        int o = (t >= off) ? s[t - off] : 0;
        __syncthreads();
        s[t] += o;
        __syncthreads();
    }
    if (idx <= N) rowptr[idx] = bsum[blockIdx.x] + s[t] - v;
}

// fill interleaved (src, weight) pairs
__global__ void k_fill(const int* __restrict__ ei, const int* __restrict__ rowptr,
                       int* __restrict__ cursor, int2* __restrict__ ep,
                       const float* __restrict__ dinv, const int* __restrict__ flags, int E) {
    int t = blockIdx.x * blockDim.x + threadIdx.x;
    if (t >= E) return;
    int wi = flags[1];
    int s = ldi(ei, t, wi);
    int d = ldi(ei, (ll)E + t, wi);
    int pos = rowptr[d] + atomicAdd(&cursor[d], 1);
    int2 v;
    v.x = s;
    v.y = __float_as_int(dinv[s] * dinv[d]);
    ep[pos] = v;
}

// ---------------- CSR aggregation: Y[n] = dinv[n]^2*X[n] + sum_e w_e * X[src_e] ----------------
// wave per node; C <= 128
template <bool EXT>
__global__ void k_agg(const void* __restrict__ X, int xstride, float* __restrict__ Y, int ystride,
                      int C, const int* __restrict__ rowptr, const int2* __restrict__ ep,
                      const float* __restrict__ dinv, const int* __restrict__ flags, int N) {
    int n = blockIdx.x * 4 + (threadIdx.x >> 6);
    if (n >= N) return;
    int lane = threadIdx.x & 63;
    int bf = EXT ? flags[0] : 0;
    float di = dinv[n];
    float w0 = di * di;
    int c1 = lane + 64;
    bool has0 = lane < C, has1 = c1 < C;
    float a0 = has0 ? w0 * ldf(X, (ll)n * xstride + lane, bf) : 0.0f;
    float a1 = has1 ? w0 * ldf(X, (ll)n * xstride + c1, bf) : 0.0f;
    int j = rowptr[n];
    int je = rowptr[n + 1];
    for (; j + 1 < je; j += 2) {
        int2 v0 = ep[j];
        int2 v1 = ep[j + 1];
        int s0 = v0.x, s1 = v1.x;
        float wa = __int_as_float(v0.y), wb = __int_as_float(v1.y);
        if (has0) {
            a0 = fmaf(wa, ldf(X, (ll)s0 * xstride + lane, bf), a0);
            a0 = fmaf(wb, ldf(X, (ll)s1 * xstride + lane, bf), a0);
        }
        if (has1) {
            a1 = fmaf(wa, ldf(X, (ll)s0 * xstride + c1, bf), a1);
            a1 = fmaf(wb, ldf(X, (ll)s1 * xstride + c1, bf), a1);
        }
    }
    if (j < je) {
        int2 v0 = ep[j];
        int s0 = v0.x;
        float wa = __int_as_float(v0.y);
        if (has0) a0 = fmaf(wa, ldf(X, (ll)s0 * xstride + lane, bf), a0);
        if (has1) a1 = fmaf(wa, ldf(X, (ll)s0 * xstride + c1, bf), a1);
    }
    if (has0) Y[(ll)n * ystride + lane] = a0;
    if (has1) Y[(ll)n * ystride + c1] = a1;
}

// ---------------- register-tiled GEMM: Y = act(X @ W + b), W/b pre-converted f32 ----------------
// `#pragma unroll 4` on the compute loop is load-bearing: full unroll hoists 40 iterations of LDS
// loads -> 360+ live VGPRs -> scratch spill (R6: 258 MB HBM/dispatch, 194 µs; R7 fixed: <25 µs).
template <int KP, int OUT, int RN, bool RELU, bool BIAS, bool BF16_IN, bool BF16_OUT>
__global__ __launch_bounds__(256) void k_gemm(const void* __restrict__ Xv, int xstride,
                                              void* __restrict__ Yv, int ystride,
                                              const float* __restrict__ W,
                                              const float* __restrict__ bias, int N) {
    constexpr int OUTP = 16 * RN;
    constexpr int BK = 40;
    constexpr int NCH = (KP + BK - 1) / BK;
    __shared__ float Xs[BK][68];
    __shared__ float Ws[BK][OUTP];
    const int tid = threadIdx.x;
    const int tn = tid & 15, to = tid >> 4;
    const int node0 = blockIdx.x * 64;
    float acc[4][RN];
#pragma unroll
    for (int m = 0; m < 4; ++m)
#pragma unroll
        for (int j = 0; j < RN; ++j) acc[m][j] = 0.0f;
    float bv[RN];
#pragma unroll
    for (int j = 0; j < RN; ++j) {
        int o = to * RN + j;
        bv[j] = (BIAS && o < OUT) ? bias[o] : 0.0f;
    }
    const int nn = tid >> 2;
    const int kb = (tid & 3) * 10;
    const ll xrow = (ll)(node0 + nn) * xstride + kb;
    for (int c = 0; c < NCH; ++c) {
        const int k0 = c * BK;
        __syncthreads();
#pragma unroll
        for (int i = 0; i < 10; ++i) Xs[kb + i][nn] = ldx<BF16_IN>(Xv, xrow + k0 + i);
        for (int idx = tid; idx < BK * OUTP; idx += 256) {
            int k = idx / OUTP, o = idx - k * OUTP;
            int kg = k0 + k;
            float v = 0.0f;
            if (kg < KP && o < OUT) v = W[(ll)kg * OUT + o];
            Ws[k][o] = v;
        }
        __syncthreads();
#pragma unroll 4
        for (int k = 0; k < BK; ++k) {
            float4 x4 = *(const float4*)&Xs[k][tn * 4];
            float wv[RN];
#pragma unroll
            for (int j = 0; j < RN; ++j) wv[j] = Ws[k][to * RN + j];
#pragma unroll
            for (int j = 0; j < RN; ++j) {
                acc[0][j] = fmaf(x4.x, wv[j], acc[0][j]);
                acc[1][j] = fmaf(x4.y, wv[j], acc[1][j]);
                acc[2][j] = fmaf(x4.z, wv[j], acc[2][j]);
                acc[3][j] = fmaf(x4.w, wv[j], acc[3][j]);
            }
        }
    }
#pragma unroll
    for (int m = 0; m < 4; ++m) {
        int n = node0 + tn * 4 + m;
        if (n >= N) continue;
#pragma unroll
        for (int j = 0; j < RN; ++j) {
            int o = to * RN + j;
            if (o >= OUT) continue;
            float v = acc[m][j] + bv[j];
            if (RELU) v = fmaxf(v, 0.0f);
            stf<BF16_OUT>(Yv, (ll)n * ystride + o, v);
        }
    }
}

// ---------------- pooled init ----------------
__global__ void k_pool_init(unsigned* pooled) {
    int t = threadIdx.x;
    if (t < 64 * 3) pooled[t] = ENC_NEG_INF;
}

// ---------------- head: z = relu(Y3 + b3) @ Wo + bo; hierarchical segment-max ----------------
__global__ void k_head(const float* __restrict__ Y3, int ystride, const float* __restrict__ wf,
                       const int* __restrict__ batch, unsigned* __restrict__ pooled,
                       const int* __restrict__ flags, int N) {
    __shared__ float Ws[50 * 3];
    __shared__ float bs[50];
    __shared__ float bos[3];
    __shared__ unsigned lmax[192];
    int wi = flags[1];
    for (int i = threadIdx.x; i < 150; i += blockDim.x) Ws[i] = wf[O_WO + i];
    for (int i = threadIdx.x; i < 50; i += blockDim.x) bs[i] = wf[O_B3 + i];
    if (threadIdx.x < 3) bos[threadIdx.x] = wf[O_BO + threadIdx.x];
    for (int i = threadIdx.x; i < 192; i += blockDim.x) lmax[i] = ENC_NEG_INF;
    __syncthreads();
    int n = blockIdx.x * blockDim.x + threadIdx.x;
    int lane = threadIdx.x & 63;
    float z0 = 0.0f, z1 = 0.0f, z2 = 0.0f;
    int g = 0;
    if (n < N) {
        z0 = bos[0];
        z1 = bos[1];
        z2 = bos[2];
        const float* y = Y3 + (ll)n * ystride;
#pragma unroll
        for (int k = 0; k < 50; ++k) {
            float h = fmaxf(y[k] + bs[k], 0.0f);
            z0 = fmaf(h, Ws[k * 3 + 0], z0);
            z1 = fmaf(h, Ws[k * 3 + 1], z1);
            z2 = fmaf(h, Ws[k * 3 + 2], z2);
        }
        g = ldi(batch, n, wi);
    }
    int g0 = __shfl(g, 0);
    unsigned long long uni = __ballot(n < N && g == g0);
    if (uni == ~0ULL) {
#pragma unroll
        for (int off = 32; off > 0; off >>= 1) {
            z0 = fmaxf(z0, __shfl_xor(z0, off));
            z1 = fmaxf(z1, __shfl_xor(z1, off));
            z2 = fmaxf(z2, __shfl_xor(z2, off));
        }
        if (lane == 0) {
            atomicMax(&lmax[g0 * 3 + 0], fenc(z0));
            atomicMax(&lmax[g0 * 3 + 1], fenc(z1));
            atomicMax(&lmax[g0 * 3 + 2], fenc(z2));
        }
    } else if (n < N) {
        atomicMax(&lmax[g * 3 + 0], fenc(z0));
        atomicMax(&lmax[g * 3 + 1], fenc(z1));
        atomicMax(&lmax[g * 3 + 2], fenc(z2));
    }
    __syncthreads();
    for (int i = threadIdx.x; i < 192; i += blockDim.x) {
        unsigned v = lmax[i];
        if (v != ENC_NEG_INF) atomicMax(&pooled[i], v);
    }
}

// ---------------- softmax over [64,3] ----------------
__global__ void k_softmax(const unsigned* __restrict__ pooled, void* __restrict__ out,
                          const int* __restrict__ flags) {
    int g = threadIdx.x;
    if (g >= 64) return;
    int bf = flags[0];
    float a = fdec(pooled[g * 3 + 0]);
    float b = fdec(pooled[g * 3 + 1]);
    float c = fdec(pooled[g * 3 + 2]);
    float m = fmaxf(a, fmaxf(b, c));
    float ea = __expf(a - m), eb = __expf(b - m), ec = __expf(c - m);
    float s = 1.0f / (ea + eb + ec);
    if (bf) {
        __hip_bfloat16* o = (__hip_bfloat16*)out;
        o[g * 3 + 0] = __float2bfloat16(ea * s);
        o[g * 3 + 1] = __float2bfloat16(eb * s);
        o[g * 3 + 2] = __float2bfloat16(ec * s);
    } else {
        float* o = (float*)out;
        o[g * 3 + 0] = ea * s;
        o[g * 3 + 1] = eb * s;
        o[g * 3 + 2] = ec * s;
    }
}

extern "C" void kernel_launch(void* const* d_in, const int* in_sizes, int n_in,
                              void* d_out, int out_size, void* d_ws, size_t ws_size,
                              hipStream_t stream) {
    const void* x = d_in[0];
    const int* ei = (const int*)d_in[1];
    const int* batch = (const int*)d_in[2];

    const int N = in_sizes[0] / 36;
    const int E = in_sizes[1] / 2;

    // ---- workspace carve ----
    char* ws = (char*)d_ws;
    size_t off = 0;
    auto carve = [&](size_t bytes) {
        char* p = ws + off;
        off = (off + bytes + 255) & ~(size_t)255;
        return p;
    };
    int* flags = (int*)carve(16);
    float* wf = (float*)carve((size_t)N_WF * 4);  // f32 weight pool
    float* dinv = (float*)carve((size_t)N * 4);
    int* cnt = (int*)carve((size_t)N * 4);
    int* rowptr = (int*)carve((size_t)(N + 1) * 4);
    int2* ep = (int2*)carve((size_t)E * 8);  // interleaved (src, weight)
    unsigned* pooled = (unsigned*)carve(768);
    const int NB = DIV_UP(N + 1, 256);
    int* bsum = (int*)carve((size_t)NB * 4);
    char* R1 = carve((size_t)N * 304);  // A1 f32 s76 | A2 f32 s76 | T3 f32 s76
    char* R2 = carve((size_t)N * 304);  // H1 f32 s76 | H2 bf16 s152 | Y3 f32 s76
    (void)carve(65536);                 // pad: unguarded GEMM staging may overread past R2

    const int B = 256;

    // 0. dtype detection + weight conversion
    k_detect<<<1, 256, 0, stream>>>((const unsigned*)x, (const unsigned*)ei, flags);
    k_cvt<<<DIV_UP(N_WF, B), B, 0, stream>>>(d_in[3], d_in[4], d_in[5], d_in[6], d_in[7], d_in[8],
                                             d_in[9], d_in[10], wf, flags);

    // 1. CSR build (multi-block scan; k_scan1 fuses dinv)
    k_zero<<<DIV_UP(N, B), B, 0, stream>>>(cnt, N);
    k_hist<<<DIV_UP(E, B), B, 0, stream>>>(ei, cnt, flags, E);
    k_scan1<<<NB, 256, 0, stream>>>(cnt, bsum, dinv, N);
    k_scan2<<<1, 256, 0, stream>>>(bsum, NB);
    k_scan3<<<NB, 256, 0, stream>>>(cnt, bsum, rowptr, N);
    k_zero<<<DIV_UP(N, B), B, 0, stream>>>(cnt, N);
    k_fill<<<DIV_UP(E, B), B, 0, stream>>>(ei, rowptr, cnt, ep, dinv, flags, E);

    // 2. layer 1: aggregate x (36) -> A1, GEMM 36->75 relu -> H1
    k_agg<true><<<DIV_UP(N, 4), B, 0, stream>>>(x, 36, (float*)R1, 76, 36, rowptr, ep, dinv, flags,
                                                N);
    k_gemm<36, 75, 5, true, true, false, false>
        <<<DIV_UP(N, 64), B, 0, stream>>>(R1, 76, R2, 76, wf + O_W1, wf + O_B1, N);

    // 3. layer 2: aggregate H1 (75) -> A2, GEMM 75->150 relu -> H2 (bf16)
    k_agg<false><<<DIV_UP(N, 4), B, 0, stream>>>(R2, 76, (float*)R1, 76, 75, rowptr, ep, dinv,
                                                 flags, N);
    k_gemm<75, 150, 10, true, true, false, true>
        <<<DIV_UP(N, 64), B, 0, stream>>>(R1, 76, R2, 152, wf + O_W2, wf + O_B2, N);

    // 4. layer 3: GEMM 150->50 (no act) -> T3, aggregate (50) -> Y3
    k_gemm<150, 50, 4, false, false, true, false>
        <<<DIV_UP(N, 64), B, 0, stream>>>(R2, 152, R1, 76, wf + O_W3, nullptr, N);
    k_agg<false><<<DIV_UP(N, 4), B, 0, stream>>>(R1, 76, (float*)R2, 76, 50, rowptr, ep, dinv,
                                                 flags, N);

    // 5. head + pooling + softmax
    k_pool_init<<<1, 192, 0, stream>>>(pooled);
    k_head<<<DIV_UP(N, B), B, 0, stream>>>((const float*)R2, 76, wf, batch, pooled, flags, N);
    k_softmax<<<1, 64, 0, stream>>>(pooled, d_out, flags);
}

// Round 9
// 369.135 us; speedup vs baseline: 3.6767x; 1.0257x over previous
//
#include <hip/hip_runtime.h>
#include <hip/hip_bf16.h>

#define DIV_UP(a, b) (((a) + (b) - 1) / (b))
typedef long long ll;

// ---------- runtime-dtype helpers ----------
__device__ __forceinline__ float ldf(const void* p, ll i, int bf) {
    return bf ? __bfloat162float(((const __hip_bfloat16*)p)[i]) : ((const float*)p)[i];
}
__device__ __forceinline__ int ldi(const int* p, ll i, int w) {
    return w ? p[2 * i] : p[i];
}
template <bool BF16>
__device__ __forceinline__ float ldx(const void* p, ll i) {
    return BF16 ? __bfloat162float(((const __hip_bfloat16*)p)[i]) : ((const float*)p)[i];
}
template <bool BF16>
__device__ __forceinline__ void stf(void* p, ll i, float v) {
    if (BF16)
        ((__hip_bfloat16*)p)[i] = __float2bfloat16(v);
    else
        ((float*)p)[i] = v;
}
// MODE: 0 = f32, 1 = bf16 (compile-time), 2 = external (runtime bf flag)
template <int MODE>
__device__ __forceinline__ float ldm(const void* p, ll i, int bf) {
    if (MODE == 0) return ((const float*)p)[i];
    if (MODE == 1) return __bfloat162float(((const __hip_bfloat16*)p)[i]);
    return ldf(p, i, bf);
}

// ---- ordered-uint encoding for float atomicMax ----
__device__ __forceinline__ unsigned fenc(float f) {
    unsigned u = __float_as_uint(f);
    return (u & 0x80000000u) ? ~u : (u | 0x80000000u);
}
__device__ __forceinline__ float fdec(unsigned u) {
    unsigned v = (u & 0x80000000u) ? (u & 0x7FFFFFFFu) : ~u;
    return __uint_as_float(v);
}
#define ENC_NEG_INF 0x007FFFFFu

// ---- weight pool offsets (f32 elements) ----
#define O_W1 0
#define O_W2 2700
#define O_W3 13950
#define O_WO 21450
#define O_B1 21600
#define O_B2 21675
#define O_B3 21825
#define O_BO 21875
#define N_WF 21878

// ---------------- dtype detection (parallel, 1 block x 256) ----------------
__global__ void k_detect(const unsigned* __restrict__ xb, const unsigned* __restrict__ eb,
                         int* __restrict__ flags) {
    __shared__ int sv[2];
    int t = threadIdx.x;
    if (t < 2) sv[t] = 0;
    __syncthreads();
    unsigned e = (xb[t] >> 7) & 0xFFu;
    int vote = (e >= 115u && e <= 133u) ? 1 : 0;
    int zero = (eb[2 * t + 1] == 0u) ? 1 : 0;
    atomicAdd(&sv[0], vote);
    atomicAdd(&sv[1], zero);
    __syncthreads();
    if (t == 0) {
        flags[0] = (sv[0] > 128) ? 1 : 0;
        flags[1] = (sv[1] > 200) ? 1 : 0;
    }
}

// ---------------- convert all weights/biases to f32 pool ----------------
__global__ void k_cvt(const void* __restrict__ W1, const void* __restrict__ b1,
                      const void* __restrict__ W2, const void* __restrict__ b2,
                      const void* __restrict__ W3, const void* __restrict__ b3,
                      const void* __restrict__ Wo, const void* __restrict__ bo,
                      float* __restrict__ wf, const int* __restrict__ flags) {
    int t = blockIdx.x * blockDim.x + threadIdx.x;
    if (t >= N_WF) return;
    int bf = flags[0];
    const void* src;
    int base;
    if (t < O_W2) {
        src = W1;
        base = O_W1;
    } else if (t < O_W3) {
        src = W2;
        base = O_W2;
    } else if (t < O_WO) {
        src = W3;
        base = O_W3;
    } else if (t < O_B1) {
        src = Wo;
        base = O_WO;
    } else if (t < O_B2) {
        src = b1;
        base = O_B1;
    } else if (t < O_B3) {
        src = b2;
        base = O_B2;
    } else if (t < O_BO) {
        src = b3;
        base = O_B3;
    } else {
        src = bo;
        base = O_BO;
    }
    wf[t] = ldf(src, t - base, bf);
}

// ---------------- CSR build ----------------
__global__ void k_zero(int* p, int n) {
    int t = blockIdx.x * blockDim.x + threadIdx.x;
    if (t < n) p[t] = 0;
}
__global__ void k_hist(const int* __restrict__ ei, int* __restrict__ cnt,
                       const int* __restrict__ flags, int E) {
    int t = blockIdx.x * blockDim.x + threadIdx.x;
    if (t >= E) return;
    atomicAdd(&cnt[ldi(ei, (ll)E + t, flags[1])], 1);
}

// ---------------- multi-block exclusive scan over M=N+1 values ----------------
__global__ void k_scan1(const int* __restrict__ cnt, int* __restrict__ bsum,
                        float* __restrict__ dinv, int N) {
    __shared__ int s[256];
    int t = threadIdx.x;
    int idx = blockIdx.x * 256 + t;
    int v = (idx < N) ? cnt[idx] : 0;
    if (idx < N) dinv[idx] = rsqrtf((float)v + 1.0f);  // +1 self-loop
    s[t] = v;
    __syncthreads();
#pragma unroll
    for (int off = 128; off > 0; off >>= 1) {
        if (t < off) s[t] += s[t + off];
        __syncthreads();
    }
    if (t == 0) bsum[blockIdx.x] = s[0];
}
__global__ void k_scan2(int* __restrict__ bsum, int nb) {
    __shared__ int s[256];
    int t = threadIdx.x;
    int run = 0;
    for (int base = 0; base < nb; base += 256) {
        int i = base + t;
        int v = (i < nb) ? bsum[i] : 0;
        s[t] = v;
        __syncthreads();
        for (int off = 1; off < 256; off <<= 1) {
            int o = (t >= off) ? s[t - off] : 0;
            __syncthreads();
            s[t] += o;
            __syncthreads();
        }
        if (i < nb) bsum[i] = run + s[t] - v;
        run += s[255];
        __syncthreads();
    }
}
__global__ void k_scan3(const int* __restrict__ cnt, const int* __restrict__ bsum,
                        int* __restrict__ rowptr, int N) {
    __shared__ int s[256];
    int t = threadIdx.x;
    int idx = blockIdx.x * 256 + t;
    int v = (idx < N) ? cnt[idx] : 0;
    s[t] = v;
    __syncthreads();
    for (int off = 1; off < 256; off <<= 1) {
        int o = (t >= off) ? s[t - off] : 0;
        __syncthreads();
        s[t] += o;
        __syncthreads();
    }
    if (idx <= N) rowptr[idx] = bsum[blockIdx.x] + s[t] - v;
}

// fill interleaved (src, weight) pairs
__global__ void k_fill(const int* __restrict__ ei, const int* __restrict__ rowptr,
                       int* __restrict__ cursor, int2* __restrict__ ep,
                       const float* __restrict__ dinv, const int* __restrict__ flags, int E) {
    int t = blockIdx.x * blockDim.x + threadIdx.x;
    if (t >= E) return;
    int wi = flags[1];
    int s = ldi(ei, t, wi);
    int d = ldi(ei, (ll)E + t, wi);
    int pos = rowptr[d] + atomicAdd(&cursor[d], 1);
    int2 v;
    v.x = s;
    v.y = __float_as_int(dinv[s] * dinv[d]);
    ep[pos] = v;
}

// ---------------- CSR aggregation: Y[n] = dinv[n]^2*X[n] + sum_e w_e * X[src_e] ----------------
// wave per node; C <= 128; MODE selects X dtype (0 f32 / 1 bf16 / 2 runtime)
template <int MODE>
__global__ void k_agg(const void* __restrict__ X, int xstride, float* __restrict__ Y, int ystride,
                      int C, const int* __restrict__ rowptr, const int2* __restrict__ ep,
                      const float* __restrict__ dinv, const int* __restrict__ flags, int N) {
    int n = blockIdx.x * 4 + (threadIdx.x >> 6);
    if (n >= N) return;
    int lane = threadIdx.x & 63;
    int bf = (MODE == 2) ? flags[0] : 0;
    float di = dinv[n];
    float w0 = di * di;
    int c1 = lane + 64;
    bool has0 = lane < C, has1 = c1 < C;
    float a0 = has0 ? w0 * ldm<MODE>(X, (ll)n * xstride + lane, bf) : 0.0f;
    float a1 = has1 ? w0 * ldm<MODE>(X, (ll)n * xstride + c1, bf) : 0.0f;
    int j = rowptr[n];
    int je = rowptr[n + 1];
    for (; j + 3 < je; j += 4) {
        int2 v0 = ep[j];
        int2 v1 = ep[j + 1];
        int2 v2 = ep[j + 2];
        int2 v3 = ep[j + 3];
        float wa = __int_as_float(v0.y), wb = __int_as_float(v1.y);
        float wc = __int_as_float(v2.y), wd = __int_as_float(v3.y);
        if (has0) {
            float x0 = ldm<MODE>(X, (ll)v0.x * xstride + lane, bf);
            float x1 = ldm<MODE>(X, (ll)v1.x * xstride + lane, bf);
            float x2 = ldm<MODE>(X, (ll)v2.x * xstride + lane, bf);
            float x3 = ldm<MODE>(X, (ll)v3.x * xstride + lane, bf);
            a0 = fmaf(wa, x0, a0);
            a0 = fmaf(wb, x1, a0);
            a0 = fmaf(wc, x2, a0);
            a0 = fmaf(wd, x3, a0);
        }
        if (has1) {
            float x0 = ldm<MODE>(X, (ll)v0.x * xstride + c1, bf);
            float x1 = ldm<MODE>(X, (ll)v1.x * xstride + c1, bf);
            float x2 = ldm<MODE>(X, (ll)v2.x * xstride + c1, bf);
            float x3 = ldm<MODE>(X, (ll)v3.x * xstride + c1, bf);
            a1 = fmaf(wa, x0, a1);
            a1 = fmaf(wb, x1, a1);
            a1 = fmaf(wc, x2, a1);
            a1 = fmaf(wd, x3, a1);
        }
    }
    for (; j < je; ++j) {
        int2 v0 = ep[j];
        float wa = __int_as_float(v0.y);
        if (has0) a0 = fmaf(wa, ldm<MODE>(X, (ll)v0.x * xstride + lane, bf), a0);
        if (has1) a1 = fmaf(wa, ldm<MODE>(X, (ll)v0.x * xstride + c1, bf), a1);
    }
    if (has0) Y[(ll)n * ystride + lane] = a0;
    if (has1) Y[(ll)n * ystride + c1] = a1;
}

// ---------------- register-tiled GEMM: Y = act(X @ W + b), W/b pre-converted f32 ----------------
// `#pragma unroll 4` on the compute loop is load-bearing: full unroll hoists 40 iterations of LDS
// loads -> 360+ live VGPRs -> scratch spill (R6: 258 MB HBM/dispatch; R7 fixed).
// W slice per thread padded to RNP (multiple of 4) so wv reads are ds_read_b128 (R8: 10 scalar
// ds_read_b32 per k dominated the LDS pipe at VALUBusy 24%).
template <int KP, int OUT, int RN, bool RELU, bool BIAS, bool BF16_IN, bool BF16_OUT>
__global__ __launch_bounds__(256) void k_gemm(const void* __restrict__ Xv, int xstride,
                                              void* __restrict__ Yv, int ystride,
                                              const float* __restrict__ W,
                                              const float* __restrict__ bias, int N) {
    constexpr int RNP = (RN + 3) & ~3;
    constexpr int OUTP = 16 * RNP;
    constexpr int BK = 40;
    constexpr int NCH = (KP + BK - 1) / BK;
    __shared__ float Xs[BK][68];
    __shared__ float Ws[BK][OUTP];
    const int tid = threadIdx.x;
    const int tn = tid & 15, to = tid >> 4;
    const int node0 = blockIdx.x * 64;
    float acc[4][RN];
#pragma unroll
    for (int m = 0; m < 4; ++m)
#pragma unroll
        for (int j = 0; j < RN; ++j) acc[m][j] = 0.0f;
    float bv[RN];
#pragma unroll
    for (int j = 0; j < RN; ++j) {
        int o = to * RN + j;
        bv[j] = (BIAS && o < OUT) ? bias[o] : 0.0f;
    }
    const int nn = tid >> 2;
    const int kb = (tid & 3) * 10;
    const ll xrow = (ll)(node0 + nn) * xstride + kb;
    for (int c = 0; c < NCH; ++c) {
        const int k0 = c * BK;
        __syncthreads();
#pragma unroll
        for (int i = 0; i < 10; ++i) Xs[kb + i][nn] = ldx<BF16_IN>(Xv, xrow + k0 + i);
        for (int idx = tid; idx < BK * OUTP; idx += 256) {
            int k = idx / OUTP, o = idx - k * OUTP;
            int to_s = o / RNP, j = o - to_s * RNP;
            int kg = k0 + k, og = to_s * RN + j;
            float v = 0.0f;
            if (kg < KP && j < RN && og < OUT) v = W[(ll)kg * OUT + og];
            Ws[k][o] = v;
        }
        __syncthreads();
#pragma unroll 4
        for (int k = 0; k < BK; ++k) {
            float4 x4 = *(const float4*)&Xs[k][tn * 4];
            float wv[RNP];
            const float4* wp = (const float4*)&Ws[k][to * RNP];
#pragma unroll
            for (int q = 0; q < RNP / 4; ++q) ((float4*)wv)[q] = wp[q];
#pragma unroll
            for (int j = 0; j < RN; ++j) {
                acc[0][j] = fmaf(x4.x, wv[j], acc[0][j]);
                acc[1][j] = fmaf(x4.y, wv[j], acc[1][j]);
                acc[2][j] = fmaf(x4.z, wv[j], acc[2][j]);
                acc[3][j] = fmaf(x4.w, wv[j], acc[3][j]);
            }
        }
    }
#pragma unroll
    for (int m = 0; m < 4; ++m) {
        int n = node0 + tn * 4 + m;
        if (n >= N) continue;
#pragma unroll
        for (int j = 0; j < RN; ++j) {
            int o = to * RN + j;
            if (o >= OUT) continue;
            float v = acc[m][j] + bv[j];
            if (RELU) v = fmaxf(v, 0.0f);
            stf<BF16_OUT>(Yv, (ll)n * ystride + o, v);
        }
    }
}

// ---------------- pooled init ----------------
__global__ void k_pool_init(unsigned* pooled) {
    int t = threadIdx.x;
    if (t < 64 * 3) pooled[t] = ENC_NEG_INF;
}

// ---------------- head: z = relu(Y3 + b3) @ Wo + bo; hierarchical segment-max ----------------
__global__ void k_head(const float* __restrict__ Y3, int ystride, const float* __restrict__ wf,
                       const int* __restrict__ batch, unsigned* __restrict__ pooled,
                       const int* __restrict__ flags, int N) {
    __shared__ float Ws[50 * 3];
    __shared__ float bs[50];
    __shared__ float bos[3];
    __shared__ unsigned lmax[192];
    int wi = flags[1];
    for (int i = threadIdx.x; i < 150; i += blockDim.x) Ws[i] = wf[O_WO + i];
    for (int i = threadIdx.x; i < 50; i += blockDim.x) bs[i] = wf[O_B3 + i];
    if (threadIdx.x < 3) bos[threadIdx.x] = wf[O_BO + threadIdx.x];
    for (int i = threadIdx.x; i < 192; i += blockDim.x) lmax[i] = ENC_NEG_INF;
    __syncthreads();
    int n = blockIdx.x * blockDim.x + threadIdx.x;
    int lane = threadIdx.x & 63;
    float z0 = 0.0f, z1 = 0.0f, z2 = 0.0f;
    int g = 0;
    if (n < N) {
        z0 = bos[0];
        z1 = bos[1];
        z2 = bos[2];
        const float* y = Y3 + (ll)n * ystride;
#pragma unroll
        for (int k = 0; k < 50; ++k) {
            float h = fmaxf(y[k] + bs[k], 0.0f);
            z0 = fmaf(h, Ws[k * 3 + 0], z0);
            z1 = fmaf(h, Ws[k * 3 + 1], z1);
            z2 = fmaf(h, Ws[k * 3 + 2], z2);
        }
        g = ldi(batch, n, wi);
    }
    int g0 = __shfl(g, 0);
    unsigned long long uni = __ballot(n < N && g == g0);
    if (uni == ~0ULL) {
#pragma unroll
        for (int off = 32; off > 0; off >>= 1) {
            z0 = fmaxf(z0, __shfl_xor(z0, off));
            z1 = fmaxf(z1, __shfl_xor(z1, off));
            z2 = fmaxf(z2, __shfl_xor(z2, off));
        }
        if (lane == 0) {
            atomicMax(&lmax[g0 * 3 + 0], fenc(z0));
            atomicMax(&lmax[g0 * 3 + 1], fenc(z1));
            atomicMax(&lmax[g0 * 3 + 2], fenc(z2));
        }
    } else if (n < N) {
        atomicMax(&lmax[g * 3 + 0], fenc(z0));
        atomicMax(&lmax[g * 3 + 1], fenc(z1));
        atomicMax(&lmax[g * 3 + 2], fenc(z2));
    }
    __syncthreads();
    for (int i = threadIdx.x; i < 192; i += blockDim.x) {
        unsigned v = lmax[i];
        if (v != ENC_NEG_INF) atomicMax(&pooled[i], v);
    }
}

// ---------------- softmax over [64,3] ----------------
__global__ void k_softmax(const unsigned* __restrict__ pooled, void* __restrict__ out,
                          const int* __restrict__ flags) {
    int g = threadIdx.x;
    if (g >= 64) return;
    int bf = flags[0];
    float a = fdec(pooled[g * 3 + 0]);
    float b = fdec(pooled[g * 3 + 1]);
    float c = fdec(pooled[g * 3 + 2]);
    float m = fmaxf(a, fmaxf(b, c));
    float ea = __expf(a - m), eb = __expf(b - m), ec = __expf(c - m);
    float s = 1.0f / (ea + eb + ec);
    if (bf) {
        __hip_bfloat16* o = (__hip_bfloat16*)out;
        o[g * 3 + 0] = __float2bfloat16(ea * s);
        o[g * 3 + 1] = __float2bfloat16(eb * s);
        o[g * 3 + 2] = __float2bfloat16(ec * s);
    } else {
        float* o = (float*)out;
        o[g * 3 + 0] = ea * s;
        o[g * 3 + 1] = eb * s;
        o[g * 3 + 2] = ec * s;
    }
}

extern "C" void kernel_launch(void* const* d_in, const int* in_sizes, int n_in,
                              void* d_out, int out_size, void* d_ws, size_t ws_size,
                              hipStream_t stream) {
    const void* x = d_in[0];
    const int* ei = (const int*)d_in[1];
    const int* batch = (const int*)d_in[2];

    const int N = in_sizes[0] / 36;
    const int E = in_sizes[1] / 2;

    // ---- workspace carve ----
    char* ws = (char*)d_ws;
    size_t off = 0;
    auto carve = [&](size_t bytes) {
        char* p = ws + off;
        off = (off + bytes + 255) & ~(size_t)255;
        return p;
    };
    int* flags = (int*)carve(16);
    float* wf = (float*)carve((size_t)N_WF * 4);  // f32 weight pool
    float* dinv = (float*)carve((size_t)N * 4);
    int* cnt = (int*)carve((size_t)N * 4);
    int* rowptr = (int*)carve((size_t)(N + 1) * 4);
    int2* ep = (int2*)carve((size_t)E * 8);  // interleaved (src, weight)
    unsigned* pooled = (unsigned*)carve(768);
    const int NB = DIV_UP(N + 1, 256);
    int* bsum = (int*)carve((size_t)NB * 4);
    char* R1 = carve((size_t)N * 304);  // A1 f32 s76 | A2 f32 s76 | T3 bf16 s76
    char* R2 = carve((size_t)N * 304);  // H1 bf16 s76 | H2 bf16 s152 | Y3 f32 s76
    (void)carve(65536);                 // pad: unguarded GEMM staging may overread past R2

    const int B = 256;

    // 0. dtype detection + weight conversion
    k_detect<<<1, 256, 0, stream>>>((const unsigned*)x, (const unsigned*)ei, flags);
    k_cvt<<<DIV_UP(N_WF, B), B, 0, stream>>>(d_in[3], d_in[4], d_in[5], d_in[6], d_in[7], d_in[8],
                                             d_in[9], d_in[10], wf, flags);

    // 1. CSR build
    k_zero<<<DIV_UP(N, B), B, 0, stream>>>(cnt, N);
    k_hist<<<DIV_UP(E, B), B, 0, stream>>>(ei, cnt, flags, E);
    k_scan1<<<NB, 256, 0, stream>>>(cnt, bsum, dinv, N);
    k_scan2<<<1, 256, 0, stream>>>(bsum, NB);
    k_scan3<<<NB, 256, 0, stream>>>(cnt, bsum, rowptr, N);
    k_zero<<<DIV_UP(N, B), B, 0, stream>>>(cnt, N);
    k_fill<<<DIV_UP(E, B), B, 0, stream>>>(ei, rowptr, cnt, ep, dinv, flags, E);

    // 2. layer 1: aggregate x (36) -> A1 f32, GEMM 36->75 relu -> H1 bf16
    k_agg<2><<<DIV_UP(N, 4), B, 0, stream>>>(x, 36, (float*)R1, 76, 36, rowptr, ep, dinv, flags, N);
    k_gemm<36, 75, 5, true, true, false, true>
        <<<DIV_UP(N, 64), B, 0, stream>>>(R1, 76, R2, 76, wf + O_W1, wf + O_B1, N);

    // 3. layer 2: aggregate H1 bf16 (75) -> A2 f32, GEMM 75->150 relu -> H2 bf16
    k_agg<1><<<DIV_UP(N, 4), B, 0, stream>>>(R2, 76, (float*)R1, 76, 75, rowptr, ep, dinv, flags,
                                             N);
    k_gemm<75, 150, 10, true, true, false, true>
        <<<DIV_UP(N, 64), B, 0, stream>>>(R1, 76, R2, 152, wf + O_W2, wf + O_B2, N);

    // 4. layer 3: GEMM 150->50 (no act) -> T3 bf16, aggregate bf16 (50) -> Y3 f32
    k_gemm<150, 50, 4, false, false, true, true>
        <<<DIV_UP(N, 64), B, 0, stream>>>(R2, 152, R1, 76, wf + O_W3, nullptr, N);
    k_agg<1><<<DIV_UP(N, 4), B, 0, stream>>>(R1, 76, (float*)R2, 76, 50, rowptr, ep, dinv, flags,
                                             N);

    // 5. head + pooling + softmax
    k_pool_init<<<1, 192, 0, stream>>>(pooled);
    k_head<<<DIV_UP(N, B), B, 0, stream>>>((const float*)R2, 76, wf, batch, pooled, flags, N);
    k_softmax<<<1, 64, 0, stream>>>(pooled, d_out, flags);
}